// Round 2
// baseline (1119.320 us; speedup 1.0000x reference)
//
#include <hip/hip_runtime.h>
#include <hip/hip_bf16.h>
#include <math.h>

#define N_NODES 20000
#define F 128
#define NRBF 20
#define E_EDGES 320000
#define F3 (3 * F)   // 384
#define NCHUNK ((N_NODES + 255) / 256)   // 79

typedef __attribute__((ext_vector_type(8))) short bf16x8;
typedef __attribute__((ext_vector_type(4))) float f32x4;

__device__ __forceinline__ float silu_f(float x) {
    return x / (1.0f + __expf(-x));
}
__device__ __forceinline__ unsigned short bf_bits(float x) {
    __hip_bfloat16 b = __float2bfloat16(x);
    return *(unsigned short*)&b;
}
// split x into bf16 hi + bf16 lo (x ~ hi + lo, ~15-bit effective mantissa)
__device__ __forceinline__ void bf_split(float x, unsigned short& hi, unsigned short& lo) {
    __hip_bfloat16 h = __float2bfloat16(x);
    float hf = __bfloat162float(h);
    __hip_bfloat16 l = __float2bfloat16(x - hf);
    hi = *(unsigned short*)&h;
    lo = *(unsigned short*)&l;
}

// ---------------------------------------------------------------------------
// Weight pre-swizzle into MFMA B-fragment order (node MLP: W1, W2).
//   element(lane,j) = W[k = kc*32 + (lane>>4)*8 + j][n = ct*16 + (lane&15)]
// ---------------------------------------------------------------------------
__global__ __launch_bounds__(256) void w_swizzle_kernel(
    const float* __restrict__ W1, const float* __restrict__ W2,
    unsigned short* __restrict__ W1s, unsigned short* __restrict__ W2s)
{
    int tid = blockIdx.x * 256 + threadIdx.x;   // one thread per (ct,kc,lane)
    if (tid < 8 * 4 * 64) {
        int lane = tid & 63, kc = (tid >> 6) & 3, ct = tid >> 8;
        int n = ct * 16 + (lane & 15);
        int k0 = kc * 32 + (lane >> 4) * 8;
        #pragma unroll
        for (int j = 0; j < 8; ++j)
            W1s[tid * 8 + j] = bf_bits(W1[(k0 + j) * F + n]);
    } else if (tid < 8 * 4 * 64 + 24 * 4 * 64) {
        int t = tid - 8 * 4 * 64;
        int lane = t & 63, kc = (t >> 6) & 3, ct = t >> 8;
        int n = ct * 16 + (lane & 15);
        int k0 = kc * 32 + (lane >> 4) * 8;
        #pragma unroll
        for (int j = 0; j < 8; ++j)
            W2s[t * 8 + j] = bf_bits(W2[(k0 + j) * F3 + n]);
    }
}

// ---------------------------------------------------------------------------
// Weight pre-swizzle for the update MLP: WU||WV (128x256), M1 (256x128),
// M2 (128x384). Plain bf16 B fragments (error compensated on A side).
// ---------------------------------------------------------------------------
__global__ __launch_bounds__(256) void w_swizzle2(
    const float* __restrict__ WU, const float* __restrict__ WV,
    const float* __restrict__ M1, const float* __restrict__ M2,
    unsigned short* __restrict__ WUVs, unsigned short* __restrict__ M1s,
    unsigned short* __restrict__ M2s)
{
    int tid = blockIdx.x * 256 + threadIdx.x;
    int lane = tid & 63;
    int set = tid >> 6;
    if (set < 64) {                       // WUV: frag idx (ct*4+kc)
        int kc = set & 3, ct = set >> 2;
        int n = ct * 16 + (lane & 15);
        int k0 = kc * 32 + (lane >> 4) * 8;
        const float* W = (ct < 8) ? WU : WV;
        int nn = n & 127;
        #pragma unroll
        for (int j = 0; j < 8; ++j)
            WUVs[(size_t)(set * 64 + lane) * 8 + j] = bf_bits(W[(k0 + j) * F + nn]);
    } else if (set < 128) {               // M1: frag idx (ct*8+kc)
        int t = set - 64;
        int kc = t & 7, ct = t >> 3;
        int n = ct * 16 + (lane & 15);
        int k0 = kc * 32 + (lane >> 4) * 8;
        #pragma unroll
        for (int j = 0; j < 8; ++j)
            M1s[(size_t)(t * 64 + lane) * 8 + j] = bf_bits(M1[(k0 + j) * F + n]);
    } else if (set < 224) {               // M2: frag idx (ct*4+kc)
        int t = set - 128;
        int kc = t & 3, ct = t >> 2;
        int n = ct * 16 + (lane & 15);
        int k0 = kc * 32 + (lane >> 4) * 8;
        #pragma unroll
        for (int j = 0; j < 8; ++j)
            M2s[(size_t)(t * 64 + lane) * 8 + j] = bf_bits(M2[(k0 + j) * F3 + n]);
    }
}

// ---------------------------------------------------------------------------
// Kernel A (MFMA): h = silu(s@W1+b1)@W2 + b2, bf16 inputs / fp32 accum.
// ---------------------------------------------------------------------------
#define SLD 136   // padded row stride (elements) for LDS tiles
__global__ __launch_bounds__(256) void node_mlp_mfma(
    const float* __restrict__ s, const float* __restrict__ b1,
    const float* __restrict__ b2,
    const unsigned short* __restrict__ W1s, const unsigned short* __restrict__ W2s,
    float* __restrict__ h)
{
    __shared__ unsigned short Sl[64][SLD];        // 17408 B
    __shared__ unsigned short Hid[4][16][SLD];    // 17408 B

    const int tid = threadIdx.x;
    const int lane = tid & 63, wave = tid >> 6;
    const int m = lane & 15, quad = lane >> 4;
    const int n0 = blockIdx.x * 64;

    for (int i = tid; i < 64 * F; i += 256) {
        int r = i >> 7, c = i & 127;
        int nn = n0 + r;
        if (nn >= N_NODES) nn = N_NODES - 1;
        Sl[r][c] = bf_bits(s[(size_t)nn * F + c]);
    }
    __syncthreads();

    const int arow = wave * 16 + m;
    bf16x8 a1[4];
    #pragma unroll
    for (int kc = 0; kc < 4; ++kc)
        a1[kc] = *(const bf16x8*)&Sl[arow][kc * 32 + quad * 8];

    const bf16x8* W1f = (const bf16x8*)W1s;
    #pragma unroll
    for (int ct = 0; ct < 8; ++ct) {
        f32x4 acc = {0.f, 0.f, 0.f, 0.f};
        #pragma unroll
        for (int kc = 0; kc < 4; ++kc)
            acc = __builtin_amdgcn_mfma_f32_16x16x32_bf16(
                a1[kc], W1f[(ct * 4 + kc) * 64 + lane], acc, 0, 0, 0);
        float bias = b1[ct * 16 + m];
        #pragma unroll
        for (int r = 0; r < 4; ++r)
            Hid[wave][quad * 4 + r][ct * 16 + m] = bf_bits(silu_f(acc[r] + bias));
    }
    __syncthreads();

    bf16x8 a2[4];
    #pragma unroll
    for (int kc = 0; kc < 4; ++kc)
        a2[kc] = *(const bf16x8*)&Hid[wave][m][kc * 32 + quad * 8];

    const bf16x8* W2f = (const bf16x8*)W2s;
    #pragma unroll
    for (int ct = 0; ct < 24; ++ct) {
        f32x4 acc = {0.f, 0.f, 0.f, 0.f};
        #pragma unroll
        for (int kc = 0; kc < 4; ++kc)
            acc = __builtin_amdgcn_mfma_f32_16x16x32_bf16(
                a2[kc], W2f[(ct * 4 + kc) * 64 + lane], acc, 0, 0, 0);
        float bias = b2[ct * 16 + m];
        #pragma unroll
        for (int r = 0; r < 4; ++r) {
            int node = n0 + wave * 16 + quad * 4 + r;
            if (node < N_NODES)
                h[(size_t)node * F3 + ct * 16 + m] = acc[r] + bias;
        }
    }
}

// ---------------------------------------------------------------------------
// CSR build: histogram -> 3-phase parallel scan -> scatter (unchanged)
// ---------------------------------------------------------------------------
__global__ __launch_bounds__(256) void hist_kernel(const int* __restrict__ i_index,
                                                   int* __restrict__ counts)
{
    int e = blockIdx.x * 256 + threadIdx.x;
    if (e < E_EDGES) atomicAdd(&counts[i_index[e]], 1);
}

__global__ __launch_bounds__(256) void scan_p1(const int* __restrict__ counts,
                                               int* __restrict__ row_start,
                                               int* __restrict__ chunk_sum)
{
    __shared__ int buf[256];
    const int tid = threadIdx.x;
    const int idx = blockIdx.x * 256 + tid;
    int val = (idx < N_NODES) ? counts[idx] : 0;
    buf[tid] = val;
    __syncthreads();
    for (int off = 1; off < 256; off <<= 1) {
        int t = (tid >= off) ? buf[tid - off] : 0;
        __syncthreads();
        buf[tid] += t;
        __syncthreads();
    }
    if (idx < N_NODES) row_start[idx] = buf[tid] - val;
    if (tid == 255) chunk_sum[blockIdx.x] = buf[255];
}

__global__ __launch_bounds__(128) void scan_p2(const int* __restrict__ chunk_sum,
                                               int* __restrict__ chunk_off)
{
    __shared__ int buf[128];
    const int tid = threadIdx.x;
    int val = (tid < NCHUNK) ? chunk_sum[tid] : 0;
    buf[tid] = val;
    __syncthreads();
    for (int off = 1; off < 128; off <<= 1) {
        int t = (tid >= off) ? buf[tid - off] : 0;
        __syncthreads();
        buf[tid] += t;
        __syncthreads();
    }
    if (tid < NCHUNK) chunk_off[tid] = buf[tid] - val;
}

__global__ __launch_bounds__(256) void scan_p3(int* __restrict__ row_start,
                                               const int* __restrict__ chunk_off,
                                               int* __restrict__ cursor)
{
    int idx = blockIdx.x * 256 + threadIdx.x;
    if (idx < N_NODES) {
        int vv = row_start[idx] + chunk_off[blockIdx.x];
        row_start[idx] = vv;
        cursor[idx] = vv;
    }
    if (idx == 0) row_start[N_NODES] = E_EDGES;
}

__global__ __launch_bounds__(256) void scatter_kernel(const int* __restrict__ i_index,
                                                      int* __restrict__ cursor,
                                                      int* __restrict__ edge_ids)
{
    int e = blockIdx.x * 256 + threadIdx.x;
    if (e < E_EDGES) {
        int pos = atomicAdd(&cursor[i_index[e]], 1);
        edge_ids[pos] = e;
    }
}

// ---------------------------------------------------------------------------
// Kernel B: per-destination-node aggregation.
// __launch_bounds__(128,4): VGPR budget 128/wave so the 60 per-thread Wr
// weights stay register-resident (was rematerialized-per-edge at VGPR=48).
// Two-edge interleaved unroll: both edges' index chains + gathers issued
// up front; rbf rows as float4 broadcast loads; 32-bit addressing.
// Pure fp32 — numerics unchanged (accumulation order trivially reordered).
// ---------------------------------------------------------------------------
__global__ __launch_bounds__(128, 4) void agg_kernel(
    const float* __restrict__ s, const float* __restrict__ v,
    const float* __restrict__ rbf, const float* __restrict__ dir,
    const int* __restrict__ j_index,
    const float* __restrict__ Wr, const float* __restrict__ br,
    const float* __restrict__ h,
    const int* __restrict__ row_start, const int* __restrict__ edge_ids,
    float* __restrict__ s_agg, float* __restrict__ v_agg)
{
    const int f = threadIdx.x;
    const int n = blockIdx.x;

    float wr0[NRBF], wr1[NRBF], wr2[NRBF];
    #pragma unroll
    for (int k = 0; k < NRBF; ++k) {
        wr0[k] = Wr[k * F3 + f];
        wr1[k] = Wr[k * F3 + F + f];
        wr2[k] = Wr[k * F3 + 2 * F + f];
    }
    const float br0 = br[f], br1 = br[F + f], br2 = br[2 * F + f];

    float s_acc = s[n * F + f];
    const float* vf = v + f * 3;
    float v0 = vf[n * F3 + 0];
    float v1 = vf[n * F3 + 1];
    float v2 = vf[n * F3 + 2];

    int idx = row_start[n];
    const int end = row_start[n + 1];
    const float cc = 0.6283185307179586f;   // pi/5

    for (; idx + 2 <= end; idx += 2) {
        const int e0 = edge_ids[idx];
        const int e1 = edge_ids[idx + 1];
        const int j0 = j_index[e0];
        const int j1 = j_index[e1];

        const float* hj0 = h + j0 * F3;
        const float* hj1 = h + j1 * F3;
        const float* vp0 = vf + j0 * F3;
        const float* vp1 = vf + j1 * F3;
        const float* dp0 = dir + e0 * 3;
        const float* dp1 = dir + e1 * 3;
        const f32x4* rp0 = (const f32x4*)(rbf + e0 * NRBF);
        const f32x4* rp1 = (const f32x4*)(rbf + e1 * NRBF);

        // gathers for both edges (issued early, independent streams)
        float h0s = hj0[f], h0vs = hj0[F + f], h0vv = hj0[2 * F + f];
        float h1s = hj1[f], h1vs = hj1[F + f], h1vv = hj1[2 * F + f];
        float a0 = vp0[0], a1 = vp0[1], a2 = vp0[2];
        float c0 = vp1[0], c1 = vp1[1], c2 = vp1[2];
        float d0x = dp0[0], d0y = dp0[1], d0z = dp0[2];
        float d1x = dp1[0], d1y = dp1[1], d1z = dp1[2];

        float x00 = br0, x01 = br1, x02 = br2;
        float x10 = br0, x11 = br1, x12 = br2;
        #pragma unroll
        for (int q = 0; q < 5; ++q) {
            f32x4 r0 = rp0[q];
            f32x4 r1 = rp1[q];
            #pragma unroll
            for (int t = 0; t < 4; ++t) {
                const int k = q * 4 + t;
                x00 += r0[t] * wr0[k];
                x01 += r0[t] * wr1[k];
                x02 += r0[t] * wr2[k];
                x10 += r1[t] * wr0[k];
                x11 += r1[t] * wr1[k];
                x12 += r1[t] * wr2[k];
            }
        }

        float w00 = (x00 < 5.0f) ? 0.5f * (__cosf(x00 * cc) + 1.0f) : 0.0f;
        float w01 = (x01 < 5.0f) ? 0.5f * (__cosf(x01 * cc) + 1.0f) : 0.0f;
        float w02 = (x02 < 5.0f) ? 0.5f * (__cosf(x02 * cc) + 1.0f) : 0.0f;
        float w10 = (x10 < 5.0f) ? 0.5f * (__cosf(x10 * cc) + 1.0f) : 0.0f;
        float w11 = (x11 < 5.0f) ? 0.5f * (__cosf(x11 * cc) + 1.0f) : 0.0f;
        float w12 = (x12 < 5.0f) ? 0.5f * (__cosf(x12 * cc) + 1.0f) : 0.0f;

        s_acc += h0s * w00 + h1s * w10;
        float g0 = h0vs * w01, u0 = h0vv * w02;
        float g1 = h1vs * w11, u1 = h1vv * w12;
        v0 += g0 * d0x + u0 * a0 + g1 * d1x + u1 * c0;
        v1 += g0 * d0y + u0 * a1 + g1 * d1y + u1 * c1;
        v2 += g0 * d0z + u0 * a2 + g1 * d1z + u1 * c2;
    }

    if (idx < end) {   // tail edge
        const int e = edge_ids[idx];
        const int j = j_index[e];
        const float* hj = h + j * F3;
        const float* vp = vf + j * F3;
        const float* dp = dir + e * 3;
        const f32x4* rp = (const f32x4*)(rbf + e * NRBF);

        float hs = hj[f], hvs = hj[F + f], hvv = hj[2 * F + f];
        float a0 = vp[0], a1 = vp[1], a2 = vp[2];
        float dx = dp[0], dy = dp[1], dz = dp[2];

        float x0 = br0, x1 = br1, x2 = br2;
        #pragma unroll
        for (int q = 0; q < 5; ++q) {
            f32x4 r = rp[q];
            #pragma unroll
            for (int t = 0; t < 4; ++t) {
                const int k = q * 4 + t;
                x0 += r[t] * wr0[k];
                x1 += r[t] * wr1[k];
                x2 += r[t] * wr2[k];
            }
        }
        float w0 = (x0 < 5.0f) ? 0.5f * (__cosf(x0 * cc) + 1.0f) : 0.0f;
        float w1 = (x1 < 5.0f) ? 0.5f * (__cosf(x1 * cc) + 1.0f) : 0.0f;
        float w2 = (x2 < 5.0f) ? 0.5f * (__cosf(x2 * cc) + 1.0f) : 0.0f;

        s_acc += hs * w0;
        float g = hvs * w1, u = hvv * w2;
        v0 += g * dx + u * a0;
        v1 += g * dy + u * a1;
        v2 += g * dz + u * a2;
    }

    s_agg[n * F + f] = s_acc;
    v_agg[n * F3 + f * 3 + 0] = v0;
    v_agg[n * F3 + f * 3 + 1] = v1;
    v_agg[n * F3 + f * 3 + 2] = v2;
}

// ---------------------------------------------------------------------------
// Kernel C: per-node update via MFMA (unchanged from R0).
// ---------------------------------------------------------------------------
#define UB 16
__global__ __launch_bounds__(256) void update_mfma(
    const float* __restrict__ s_agg, const float* __restrict__ v_agg,
    const unsigned short* __restrict__ WUVs,
    const float* __restrict__ bU, const float* __restrict__ bV,
    const unsigned short* __restrict__ M1s, const float* __restrict__ bm1,
    const unsigned short* __restrict__ M2s, const float* __restrict__ bm2,
    float* __restrict__ s_out, float* __restrict__ v_out)
{
    __shared__ unsigned short VAh[48][SLD],  VAl[48][SLD];
    __shared__ unsigned short MIh[16][264],  MIl[16][264];
    __shared__ unsigned short HIh[16][SLD],  HIl[16][SLD];

    const int tid = threadIdx.x;
    const int lane = tid & 63, wave = tid >> 6;
    const int m = lane & 15, quad = lane >> 4;
    const int n0 = blockIdx.x * UB;

    for (int i = tid; i < UB * F3; i += 256) {
        int nl = i / F3, r = i - nl * F3;
        int f = r / 3, d = r - f * 3;
        unsigned short hi, lo;
        bf_split(v_agg[(size_t)n0 * F3 + i], hi, lo);
        VAh[d * 16 + nl][f] = hi;
        VAl[d * 16 + nl][f] = lo;
    }
    __syncthreads();

    f32x4 accU[3][2], accV[3][2];
    #pragma unroll
    for (int d = 0; d < 3; ++d)
        #pragma unroll
        for (int c = 0; c < 2; ++c) {
            accU[d][c] = (f32x4){0.f, 0.f, 0.f, 0.f};
            accV[d][c] = (f32x4){0.f, 0.f, 0.f, 0.f};
        }

    const bf16x8* Wf  = (const bf16x8*)WUVs;
    #pragma unroll
    for (int kc = 0; kc < 4; ++kc) {
        bf16x8 bu0 = Wf[((wave * 2 + 0) * 4 + kc) * 64 + lane];
        bf16x8 bu1 = Wf[((wave * 2 + 1) * 4 + kc) * 64 + lane];
        bf16x8 bv0 = Wf[((8 + wave * 2 + 0) * 4 + kc) * 64 + lane];
        bf16x8 bv1 = Wf[((8 + wave * 2 + 1) * 4 + kc) * 64 + lane];
        #pragma unroll
        for (int d = 0; d < 3; ++d) {
            bf16x8 ah = *(const bf16x8*)&VAh[d * 16 + m][kc * 32 + quad * 8];
            bf16x8 al = *(const bf16x8*)&VAl[d * 16 + m][kc * 32 + quad * 8];
            accU[d][0] = __builtin_amdgcn_mfma_f32_16x16x32_bf16(ah, bu0, accU[d][0], 0, 0, 0);
            accU[d][0] = __builtin_amdgcn_mfma_f32_16x16x32_bf16(al, bu0, accU[d][0], 0, 0, 0);
            accU[d][1] = __builtin_amdgcn_mfma_f32_16x16x32_bf16(ah, bu1, accU[d][1], 0, 0, 0);
            accU[d][1] = __builtin_amdgcn_mfma_f32_16x16x32_bf16(al, bu1, accU[d][1], 0, 0, 0);
            accV[d][0] = __builtin_amdgcn_mfma_f32_16x16x32_bf16(ah, bv0, accV[d][0], 0, 0, 0);
            accV[d][0] = __builtin_amdgcn_mfma_f32_16x16x32_bf16(al, bv0, accV[d][0], 0, 0, 0);
            accV[d][1] = __builtin_amdgcn_mfma_f32_16x16x32_bf16(ah, bv1, accV[d][1], 0, 0, 0);
            accV[d][1] = __builtin_amdgcn_mfma_f32_16x16x32_bf16(al, bv1, accV[d][1], 0, 0, 0);
        }
    }

    #pragma unroll
    for (int c = 0; c < 2; ++c) {
        int g = wave * 32 + c * 16 + m;
        float bu = bU[g], bv = bV[g];
        #pragma unroll
        for (int d = 0; d < 3; ++d)
            #pragma unroll
            for (int r = 0; r < 4; ++r) {
                accU[d][c][r] += bu;
                accV[d][c][r] += bv;
            }
        #pragma unroll
        for (int r = 0; r < 4; ++r) {
            int nl = quad * 4 + r;
            float nv = sqrtf(accV[0][c][r] * accV[0][c][r] +
                             accV[1][c][r] * accV[1][c][r] +
                             accV[2][c][r] * accV[2][c][r]);
            unsigned short hi, lo;
            bf_split(nv, hi, lo);
            MIh[nl][g] = hi; MIl[nl][g] = lo;
            bf_split(s_agg[(size_t)(n0 + nl) * F + g], hi, lo);
            MIh[nl][128 + g] = hi; MIl[nl][128 + g] = lo;
        }
    }
    __syncthreads();

    f32x4 acc2[2];
    acc2[0] = (f32x4){0.f, 0.f, 0.f, 0.f};
    acc2[1] = (f32x4){0.f, 0.f, 0.f, 0.f};
    const bf16x8* M1f = (const bf16x8*)M1s;
    #pragma unroll
    for (int kc = 0; kc < 8; ++kc) {
        bf16x8 ah = *(const bf16x8*)&MIh[m][kc * 32 + quad * 8];
        bf16x8 al = *(const bf16x8*)&MIl[m][kc * 32 + quad * 8];
        bf16x8 b0 = M1f[((wave * 2 + 0) * 8 + kc) * 64 + lane];
        bf16x8 b1 = M1f[((wave * 2 + 1) * 8 + kc) * 64 + lane];
        acc2[0] = __builtin_amdgcn_mfma_f32_16x16x32_bf16(ah, b0, acc2[0], 0, 0, 0);
        acc2[0] = __builtin_amdgcn_mfma_f32_16x16x32_bf16(al, b0, acc2[0], 0, 0, 0);
        acc2[1] = __builtin_amdgcn_mfma_f32_16x16x32_bf16(ah, b1, acc2[1], 0, 0, 0);
        acc2[1] = __builtin_amdgcn_mfma_f32_16x16x32_bf16(al, b1, acc2[1], 0, 0, 0);
    }
    #pragma unroll
    for (int c = 0; c < 2; ++c) {
        int g = wave * 32 + c * 16 + m;
        float bh = bm1[g];
        #pragma unroll
        for (int r = 0; r < 4; ++r) {
            unsigned short hi, lo;
            bf_split(silu_f(acc2[c][r] + bh), hi, lo);
            HIh[quad * 4 + r][g] = hi;
            HIl[quad * 4 + r][g] = lo;
        }
    }
    __syncthreads();

    f32x4 acc3[3][2];
    #pragma unroll
    for (int o = 0; o < 3; ++o)
        #pragma unroll
        for (int c = 0; c < 2; ++c)
            acc3[o][c] = (f32x4){0.f, 0.f, 0.f, 0.f};
    const bf16x8* M2f = (const bf16x8*)M2s;
    #pragma unroll
    for (int kc = 0; kc < 4; ++kc) {
        bf16x8 ah = *(const bf16x8*)&HIh[m][kc * 32 + quad * 8];
        bf16x8 al = *(const bf16x8*)&HIl[m][kc * 32 + quad * 8];
        #pragma unroll
        for (int o = 0; o < 3; ++o)
            #pragma unroll
            for (int c = 0; c < 2; ++c) {
                bf16x8 bb = M2f[(((o * 8) + wave * 2 + c) * 4 + kc) * 64 + lane];
                acc3[o][c] = __builtin_amdgcn_mfma_f32_16x16x32_bf16(ah, bb, acc3[o][c], 0, 0, 0);
                acc3[o][c] = __builtin_amdgcn_mfma_f32_16x16x32_bf16(al, bb, acc3[o][c], 0, 0, 0);
            }
    }

    #pragma unroll
    for (int c = 0; c < 2; ++c) {
        int g = wave * 32 + c * 16 + m;
        float bvv = bm2[g], bsv = bm2[128 + g], bss = bm2[256 + g];
        #pragma unroll
        for (int r = 0; r < 4; ++r) {
            int nl = quad * 4 + r;
            int n = n0 + nl;
            float a_vv = acc3[0][c][r] + bvv;
            float a_sv = acc3[1][c][r] + bsv;
            float a_ss = acc3[2][c][r] + bss;
            float dotuv = accU[0][c][r] * accV[0][c][r] +
                          accU[1][c][r] * accV[1][c][r] +
                          accU[2][c][r] * accV[2][c][r];
            s_out[(size_t)n * F + g] =
                s_agg[(size_t)n * F + g] + dotuv * a_sv + a_ss;
            #pragma unroll
            for (int d = 0; d < 3; ++d)
                v_out[(size_t)n * F3 + g * 3 + d] =
                    v_agg[(size_t)n * F3 + g * 3 + d] + a_vv * accU[d][c][r];
        }
    }
}

// ---------------------------------------------------------------------------
extern "C" void kernel_launch(void* const* d_in, const int* in_sizes, int n_in,
                              void* d_out, int out_size, void* d_ws, size_t ws_size,
                              hipStream_t stream) {
    const float* s    = (const float*)d_in[0];
    const float* v    = (const float*)d_in[1];
    const float* rbf  = (const float*)d_in[2];
    const float* dir  = (const float*)d_in[3];
    const float* W1   = (const float*)d_in[4];
    const float* b1   = (const float*)d_in[5];
    const float* W2   = (const float*)d_in[6];
    const float* b2   = (const float*)d_in[7];
    const float* Wr   = (const float*)d_in[8];
    const float* br   = (const float*)d_in[9];
    const float* WU   = (const float*)d_in[10];
    const float* bU   = (const float*)d_in[11];
    const float* WV   = (const float*)d_in[12];
    const float* bV   = (const float*)d_in[13];
    const float* M1   = (const float*)d_in[14];
    const float* bm1  = (const float*)d_in[15];
    const float* M2   = (const float*)d_in[16];
    const float* bm2  = (const float*)d_in[17];
    const int* i_index = (const int*)d_in[18];
    const int* j_index = (const int*)d_in[19];

    float* out_s = (float*)d_out;                     // N*F
    float* out_v = out_s + (size_t)N_NODES * F;       // N*F*3

    // workspace layout
    float* h       = (float*)d_ws;                         // N*384 floats
    float* s_agg   = h + (size_t)N_NODES * F3;             // N*128
    float* v_agg   = s_agg + (size_t)N_NODES * F;          // N*384
    int*   counts  = (int*)(v_agg + (size_t)N_NODES * F3); // N
    int*   row_start = counts + N_NODES;                   // N+1
    int*   cursor  = row_start + N_NODES + 1;              // N
    int*   edge_ids = cursor + N_NODES;                    // E
    int*   chunk_sum = edge_ids + E_EDGES;                 // 128
    int*   chunk_off = chunk_sum + 128;                    // 128
    unsigned short* W1s = (unsigned short*)(chunk_off + 128);  // 8*4*64*8
    unsigned short* W2s = W1s + 8 * 4 * 64 * 8;                // 24*4*64*8
    unsigned short* WUVs = W2s + 24 * 4 * 64 * 8;              // 16*4*64*8
    unsigned short* M1s  = WUVs + 16 * 4 * 64 * 8;             // 8*8*64*8
    unsigned short* M2s  = M1s + 8 * 8 * 64 * 8;               // 24*4*64*8

    hipMemsetAsync(counts, 0, sizeof(int) * N_NODES, stream);

    w_swizzle_kernel<<<32, 256, 0, stream>>>(W1, W2, W1s, W2s);
    w_swizzle2<<<56, 256, 0, stream>>>(WU, WV, M1, M2, WUVs, M1s, M2s);
    node_mlp_mfma<<<(N_NODES + 63) / 64, 256, 0, stream>>>(s, b1, b2, W1s, W2s, h);

    hist_kernel<<<(E_EDGES + 255) / 256, 256, 0, stream>>>(i_index, counts);
    scan_p1<<<NCHUNK, 256, 0, stream>>>(counts, row_start, chunk_sum);
    scan_p2<<<1, 128, 0, stream>>>(chunk_sum, chunk_off);
    scan_p3<<<NCHUNK, 256, 0, stream>>>(row_start, chunk_off, cursor);
    scatter_kernel<<<(E_EDGES + 255) / 256, 256, 0, stream>>>(i_index, cursor, edge_ids);

    agg_kernel<<<N_NODES, 128, 0, stream>>>(s, v, rbf, dir, j_index, Wr, br, h,
                                            row_start, edge_ids, s_agg, v_agg);

    update_mfma<<<N_NODES / UB, 256, 0, stream>>>(s_agg, v_agg, WUVs, bU, bV,
                                                  M1s, bm1, M2s, bm2, out_s, out_v);
}

// Round 3
// 503.978 us; speedup vs baseline: 2.2210x; 2.2210x over previous
//
#include <hip/hip_runtime.h>
#include <hip/hip_bf16.h>
#include <math.h>

#define N_NODES 20000
#define F 128
#define NRBF 20
#define E_EDGES 320000
#define F3 (3 * F)   // 384
#define NCHUNK ((N_NODES + 255) / 256)   // 79

typedef __attribute__((ext_vector_type(8))) short bf16x8;
typedef __attribute__((ext_vector_type(4))) float f32x4;

__device__ __forceinline__ float silu_f(float x) {
    return x / (1.0f + __expf(-x));
}
__device__ __forceinline__ unsigned short bf_bits(float x) {
    __hip_bfloat16 b = __float2bfloat16(x);
    return *(unsigned short*)&b;
}
// split x into bf16 hi + bf16 lo (x ~ hi + lo, ~15-bit effective mantissa)
__device__ __forceinline__ void bf_split(float x, unsigned short& hi, unsigned short& lo) {
    __hip_bfloat16 h = __float2bfloat16(x);
    float hf = __bfloat162float(h);
    __hip_bfloat16 l = __float2bfloat16(x - hf);
    hi = *(unsigned short*)&h;
    lo = *(unsigned short*)&l;
}

// ---------------------------------------------------------------------------
// Merged weight pre-swizzle (node MLP W1/W2 + update MLP WUV/M1/M2).
//   element(lane,j) = W[k = kc*32 + (lane>>4)*8 + j][n = ct*16 + (lane&15)]
// threads: W1 2048 | W2 6144 | WUV 4096 | M1 4096 | M2 6144  -> 22528
// ---------------------------------------------------------------------------
__global__ __launch_bounds__(256) void w_swizzle_all(
    const float* __restrict__ W1, const float* __restrict__ W2,
    const float* __restrict__ WU, const float* __restrict__ WV,
    const float* __restrict__ M1, const float* __restrict__ M2,
    unsigned short* __restrict__ W1s, unsigned short* __restrict__ W2s,
    unsigned short* __restrict__ WUVs, unsigned short* __restrict__ M1s,
    unsigned short* __restrict__ M2s)
{
    int tid = blockIdx.x * 256 + threadIdx.x;
    if (tid < 8 * 4 * 64) {                                // W1
        int lane = tid & 63, kc = (tid >> 6) & 3, ct = tid >> 8;
        int n = ct * 16 + (lane & 15);
        int k0 = kc * 32 + (lane >> 4) * 8;
        #pragma unroll
        for (int j = 0; j < 8; ++j)
            W1s[tid * 8 + j] = bf_bits(W1[(k0 + j) * F + n]);
    } else if (tid < 8 * 4 * 64 + 24 * 4 * 64) {           // W2
        int t = tid - 8 * 4 * 64;
        int lane = t & 63, kc = (t >> 6) & 3, ct = t >> 8;
        int n = ct * 16 + (lane & 15);
        int k0 = kc * 32 + (lane >> 4) * 8;
        #pragma unroll
        for (int j = 0; j < 8; ++j)
            W2s[t * 8 + j] = bf_bits(W2[(k0 + j) * F3 + n]);
    } else if (tid < 8192 + 224 * 64) {                    // update-MLP weights
        int t2 = tid - 8192;
        int lane = t2 & 63;
        int set = t2 >> 6;
        if (set < 64) {                       // WUV: frag idx (ct*4+kc)
            int kc = set & 3, ct = set >> 2;
            int n = ct * 16 + (lane & 15);
            int k0 = kc * 32 + (lane >> 4) * 8;
            const float* W = (ct < 8) ? WU : WV;
            int nn = n & 127;
            #pragma unroll
            for (int j = 0; j < 8; ++j)
                WUVs[(size_t)(set * 64 + lane) * 8 + j] = bf_bits(W[(k0 + j) * F + nn]);
        } else if (set < 128) {               // M1: frag idx (ct*8+kc)
            int t = set - 64;
            int kc = t & 7, ct = t >> 3;
            int n = ct * 16 + (lane & 15);
            int k0 = kc * 32 + (lane >> 4) * 8;
            #pragma unroll
            for (int j = 0; j < 8; ++j)
                M1s[(size_t)(t * 64 + lane) * 8 + j] = bf_bits(M1[(k0 + j) * F + n]);
        } else {                              // M2: frag idx (ct*4+kc)
            int t = set - 128;
            int kc = t & 3, ct = t >> 2;
            int n = ct * 16 + (lane & 15);
            int k0 = kc * 32 + (lane >> 4) * 8;
            #pragma unroll
            for (int j = 0; j < 8; ++j)
                M2s[(size_t)(t * 64 + lane) * 8 + j] = bf_bits(M2[(k0 + j) * F3 + n]);
        }
    }
}

// ---------------------------------------------------------------------------
// Kernel A (MFMA): h = silu(s@W1+b1)@W2 + b2, bf16 inputs / fp32 accum.
// ---------------------------------------------------------------------------
#define SLD 136   // padded row stride (elements) for LDS tiles
__global__ __launch_bounds__(256) void node_mlp_mfma(
    const float* __restrict__ s, const float* __restrict__ b1,
    const float* __restrict__ b2,
    const unsigned short* __restrict__ W1s, const unsigned short* __restrict__ W2s,
    float* __restrict__ h)
{
    __shared__ unsigned short Sl[64][SLD];        // 17408 B
    __shared__ unsigned short Hid[4][16][SLD];    // 17408 B

    const int tid = threadIdx.x;
    const int lane = tid & 63, wave = tid >> 6;
    const int m = lane & 15, quad = lane >> 4;
    const int n0 = blockIdx.x * 64;

    for (int i = tid; i < 64 * F; i += 256) {
        int r = i >> 7, c = i & 127;
        int nn = n0 + r;
        if (nn >= N_NODES) nn = N_NODES - 1;
        Sl[r][c] = bf_bits(s[(size_t)nn * F + c]);
    }
    __syncthreads();

    const int arow = wave * 16 + m;
    bf16x8 a1[4];
    #pragma unroll
    for (int kc = 0; kc < 4; ++kc)
        a1[kc] = *(const bf16x8*)&Sl[arow][kc * 32 + quad * 8];

    const bf16x8* W1f = (const bf16x8*)W1s;
    #pragma unroll
    for (int ct = 0; ct < 8; ++ct) {
        f32x4 acc = {0.f, 0.f, 0.f, 0.f};
        #pragma unroll
        for (int kc = 0; kc < 4; ++kc)
            acc = __builtin_amdgcn_mfma_f32_16x16x32_bf16(
                a1[kc], W1f[(ct * 4 + kc) * 64 + lane], acc, 0, 0, 0);
        float bias = b1[ct * 16 + m];
        #pragma unroll
        for (int r = 0; r < 4; ++r)
            Hid[wave][quad * 4 + r][ct * 16 + m] = bf_bits(silu_f(acc[r] + bias));
    }
    __syncthreads();

    bf16x8 a2[4];
    #pragma unroll
    for (int kc = 0; kc < 4; ++kc)
        a2[kc] = *(const bf16x8*)&Hid[wave][m][kc * 32 + quad * 8];

    const bf16x8* W2f = (const bf16x8*)W2s;
    #pragma unroll
    for (int ct = 0; ct < 24; ++ct) {
        f32x4 acc = {0.f, 0.f, 0.f, 0.f};
        #pragma unroll
        for (int kc = 0; kc < 4; ++kc)
            acc = __builtin_amdgcn_mfma_f32_16x16x32_bf16(
                a2[kc], W2f[(ct * 4 + kc) * 64 + lane], acc, 0, 0, 0);
        float bias = b2[ct * 16 + m];
        #pragma unroll
        for (int r = 0; r < 4; ++r) {
            int node = n0 + wave * 16 + quad * 4 + r;
            if (node < N_NODES)
                h[(size_t)node * F3 + ct * 16 + m] = acc[r] + bias;
        }
    }
}

// ---------------------------------------------------------------------------
// CSR build: histogram -> 3-phase parallel scan -> scatter (unchanged)
// ---------------------------------------------------------------------------
__global__ __launch_bounds__(256) void hist_kernel(const int* __restrict__ i_index,
                                                   int* __restrict__ counts)
{
    int e = blockIdx.x * 256 + threadIdx.x;
    if (e < E_EDGES) atomicAdd(&counts[i_index[e]], 1);
}

__global__ __launch_bounds__(256) void scan_p1(const int* __restrict__ counts,
                                               int* __restrict__ row_start,
                                               int* __restrict__ chunk_sum)
{
    __shared__ int buf[256];
    const int tid = threadIdx.x;
    const int idx = blockIdx.x * 256 + tid;
    int val = (idx < N_NODES) ? counts[idx] : 0;
    buf[tid] = val;
    __syncthreads();
    for (int off = 1; off < 256; off <<= 1) {
        int t = (tid >= off) ? buf[tid - off] : 0;
        __syncthreads();
        buf[tid] += t;
        __syncthreads();
    }
    if (idx < N_NODES) row_start[idx] = buf[tid] - val;
    if (tid == 255) chunk_sum[blockIdx.x] = buf[255];
}

__global__ __launch_bounds__(128) void scan_p2(const int* __restrict__ chunk_sum,
                                               int* __restrict__ chunk_off)
{
    __shared__ int buf[128];
    const int tid = threadIdx.x;
    int val = (tid < NCHUNK) ? chunk_sum[tid] : 0;
    buf[tid] = val;
    __syncthreads();
    for (int off = 1; off < 128; off <<= 1) {
        int t = (tid >= off) ? buf[tid - off] : 0;
        __syncthreads();
        buf[tid] += t;
        __syncthreads();
    }
    if (tid < NCHUNK) chunk_off[tid] = buf[tid] - val;
}

__global__ __launch_bounds__(256) void scan_p3(int* __restrict__ row_start,
                                               const int* __restrict__ chunk_off,
                                               int* __restrict__ cursor)
{
    int idx = blockIdx.x * 256 + threadIdx.x;
    if (idx < N_NODES) {
        int vv = row_start[idx] + chunk_off[blockIdx.x];
        row_start[idx] = vv;
        cursor[idx] = vv;
    }
    if (idx == 0) row_start[N_NODES] = E_EDGES;
}

__global__ __launch_bounds__(256) void scatter_kernel(const int* __restrict__ i_index,
                                                      int* __restrict__ cursor,
                                                      int* __restrict__ edge_ids)
{
    int e = blockIdx.x * 256 + threadIdx.x;
    if (e < E_EDGES) {
        int pos = atomicAdd(&cursor[i_index[e]], 1);
        edge_ids[pos] = e;
    }
}

// ---------------------------------------------------------------------------
// Kernel B: per-destination-node aggregation.
// Reverted to the proven R1 body (VGPR=48, no spill, 172 us).
// Changes vs R1 (both minimal-risk):
//  * 256-thread blocks covering 2 independent nodes (tid>>7) — tests the
//    WG-slot occupancy theory; no syncthreads, numerics identical.
//  * rbf row read as 5x float4 (80B row, 16B-aligned) instead of 20 scalars.
// NO launch_bounds occupancy arg (the (128,4) variant spilled to scratch).
// ---------------------------------------------------------------------------
__global__ __launch_bounds__(256) void agg_kernel(
    const float* __restrict__ s, const float* __restrict__ v,
    const float* __restrict__ rbf, const float* __restrict__ dir,
    const int* __restrict__ j_index,
    const float* __restrict__ Wr, const float* __restrict__ br,
    const float* __restrict__ h,
    const int* __restrict__ row_start, const int* __restrict__ edge_ids,
    float* __restrict__ s_agg, float* __restrict__ v_agg)
{
    const int f = threadIdx.x & 127;
    const int n = blockIdx.x * 2 + (threadIdx.x >> 7);

    float wr0[NRBF], wr1[NRBF], wr2[NRBF];
    #pragma unroll
    for (int k = 0; k < NRBF; ++k) {
        wr0[k] = Wr[k * F3 + f];
        wr1[k] = Wr[k * F3 + F + f];
        wr2[k] = Wr[k * F3 + 2 * F + f];
    }
    const float br0 = br[f], br1 = br[F + f], br2 = br[2 * F + f];

    float s_acc = s[(size_t)n * F + f];
    float v0 = v[(size_t)n * F3 + f * 3 + 0];
    float v1 = v[(size_t)n * F3 + f * 3 + 1];
    float v2 = v[(size_t)n * F3 + f * 3 + 2];

    const int beg = row_start[n];
    const int end = row_start[n + 1];
    const float cc = 0.6283185307179586f;   // pi/5

    for (int idx = beg; idx < end; ++idx) {
        const int e = edge_ids[idx];
        const int j = j_index[e];

        float x0 = br0, x1 = br1, x2 = br2;
        const f32x4* rp = (const f32x4*)(rbf + (size_t)e * NRBF);
        #pragma unroll
        for (int q = 0; q < 5; ++q) {
            f32x4 rq = rp[q];
            #pragma unroll
            for (int t = 0; t < 4; ++t) {
                const int k = q * 4 + t;
                x0 += rq[t] * wr0[k];
                x1 += rq[t] * wr1[k];
                x2 += rq[t] * wr2[k];
            }
        }
        float w0 = (x0 < 5.0f) ? 0.5f * (__cosf(x0 * cc) + 1.0f) : 0.0f;
        float w1 = (x1 < 5.0f) ? 0.5f * (__cosf(x1 * cc) + 1.0f) : 0.0f;
        float w2 = (x2 < 5.0f) ? 0.5f * (__cosf(x2 * cc) + 1.0f) : 0.0f;

        float hs  = h[(size_t)j * F3 + f]         * w0;
        float hvs = h[(size_t)j * F3 + F + f]     * w1;
        float hvv = h[(size_t)j * F3 + 2 * F + f] * w2;

        float dx = dir[(size_t)e * 3 + 0];
        float dy = dir[(size_t)e * 3 + 1];
        float dz = dir[(size_t)e * 3 + 2];

        float vj0 = v[(size_t)j * F3 + f * 3 + 0];
        float vj1 = v[(size_t)j * F3 + f * 3 + 1];
        float vj2 = v[(size_t)j * F3 + f * 3 + 2];

        s_acc += hs;
        v0 += hvs * dx + hvv * vj0;
        v1 += hvs * dy + hvv * vj1;
        v2 += hvs * dz + hvv * vj2;
    }

    s_agg[(size_t)n * F + f] = s_acc;
    v_agg[(size_t)n * F3 + f * 3 + 0] = v0;
    v_agg[(size_t)n * F3 + f * 3 + 1] = v1;
    v_agg[(size_t)n * F3 + f * 3 + 2] = v2;
}

// ---------------------------------------------------------------------------
// Kernel C: per-node update via MFMA (unchanged from R1).
// ---------------------------------------------------------------------------
#define UB 16
__global__ __launch_bounds__(256) void update_mfma(
    const float* __restrict__ s_agg, const float* __restrict__ v_agg,
    const unsigned short* __restrict__ WUVs,
    const float* __restrict__ bU, const float* __restrict__ bV,
    const unsigned short* __restrict__ M1s, const float* __restrict__ bm1,
    const unsigned short* __restrict__ M2s, const float* __restrict__ bm2,
    float* __restrict__ s_out, float* __restrict__ v_out)
{
    __shared__ unsigned short VAh[48][SLD],  VAl[48][SLD];
    __shared__ unsigned short MIh[16][264],  MIl[16][264];
    __shared__ unsigned short HIh[16][SLD],  HIl[16][SLD];

    const int tid = threadIdx.x;
    const int lane = tid & 63, wave = tid >> 6;
    const int m = lane & 15, quad = lane >> 4;
    const int n0 = blockIdx.x * UB;

    for (int i = tid; i < UB * F3; i += 256) {
        int nl = i / F3, r = i - nl * F3;
        int f = r / 3, d = r - f * 3;
        unsigned short hi, lo;
        bf_split(v_agg[(size_t)n0 * F3 + i], hi, lo);
        VAh[d * 16 + nl][f] = hi;
        VAl[d * 16 + nl][f] = lo;
    }
    __syncthreads();

    f32x4 accU[3][2], accV[3][2];
    #pragma unroll
    for (int d = 0; d < 3; ++d)
        #pragma unroll
        for (int c = 0; c < 2; ++c) {
            accU[d][c] = (f32x4){0.f, 0.f, 0.f, 0.f};
            accV[d][c] = (f32x4){0.f, 0.f, 0.f, 0.f};
        }

    const bf16x8* Wf  = (const bf16x8*)WUVs;
    #pragma unroll
    for (int kc = 0; kc < 4; ++kc) {
        bf16x8 bu0 = Wf[((wave * 2 + 0) * 4 + kc) * 64 + lane];
        bf16x8 bu1 = Wf[((wave * 2 + 1) * 4 + kc) * 64 + lane];
        bf16x8 bv0 = Wf[((8 + wave * 2 + 0) * 4 + kc) * 64 + lane];
        bf16x8 bv1 = Wf[((8 + wave * 2 + 1) * 4 + kc) * 64 + lane];
        #pragma unroll
        for (int d = 0; d < 3; ++d) {
            bf16x8 ah = *(const bf16x8*)&VAh[d * 16 + m][kc * 32 + quad * 8];
            bf16x8 al = *(const bf16x8*)&VAl[d * 16 + m][kc * 32 + quad * 8];
            accU[d][0] = __builtin_amdgcn_mfma_f32_16x16x32_bf16(ah, bu0, accU[d][0], 0, 0, 0);
            accU[d][0] = __builtin_amdgcn_mfma_f32_16x16x32_bf16(al, bu0, accU[d][0], 0, 0, 0);
            accU[d][1] = __builtin_amdgcn_mfma_f32_16x16x32_bf16(ah, bu1, accU[d][1], 0, 0, 0);
            accU[d][1] = __builtin_amdgcn_mfma_f32_16x16x32_bf16(al, bu1, accU[d][1], 0, 0, 0);
            accV[d][0] = __builtin_amdgcn_mfma_f32_16x16x32_bf16(ah, bv0, accV[d][0], 0, 0, 0);
            accV[d][0] = __builtin_amdgcn_mfma_f32_16x16x32_bf16(al, bv0, accV[d][0], 0, 0, 0);
            accV[d][1] = __builtin_amdgcn_mfma_f32_16x16x32_bf16(ah, bv1, accV[d][1], 0, 0, 0);
            accV[d][1] = __builtin_amdgcn_mfma_f32_16x16x32_bf16(al, bv1, accV[d][1], 0, 0, 0);
        }
    }

    #pragma unroll
    for (int c = 0; c < 2; ++c) {
        int g = wave * 32 + c * 16 + m;
        float bu = bU[g], bv = bV[g];
        #pragma unroll
        for (int d = 0; d < 3; ++d)
            #pragma unroll
            for (int r = 0; r < 4; ++r) {
                accU[d][c][r] += bu;
                accV[d][c][r] += bv;
            }
        #pragma unroll
        for (int r = 0; r < 4; ++r) {
            int nl = quad * 4 + r;
            float nv = sqrtf(accV[0][c][r] * accV[0][c][r] +
                             accV[1][c][r] * accV[1][c][r] +
                             accV[2][c][r] * accV[2][c][r]);
            unsigned short hi, lo;
            bf_split(nv, hi, lo);
            MIh[nl][g] = hi; MIl[nl][g] = lo;
            bf_split(s_agg[(size_t)(n0 + nl) * F + g], hi, lo);
            MIh[nl][128 + g] = hi; MIl[nl][128 + g] = lo;
        }
    }
    __syncthreads();

    f32x4 acc2[2];
    acc2[0] = (f32x4){0.f, 0.f, 0.f, 0.f};
    acc2[1] = (f32x4){0.f, 0.f, 0.f, 0.f};
    const bf16x8* M1f = (const bf16x8*)M1s;
    #pragma unroll
    for (int kc = 0; kc < 8; ++kc) {
        bf16x8 ah = *(const bf16x8*)&MIh[m][kc * 32 + quad * 8];
        bf16x8 al = *(const bf16x8*)&MIl[m][kc * 32 + quad * 8];
        bf16x8 b0 = M1f[((wave * 2 + 0) * 8 + kc) * 64 + lane];
        bf16x8 b1 = M1f[((wave * 2 + 1) * 8 + kc) * 64 + lane];
        acc2[0] = __builtin_amdgcn_mfma_f32_16x16x32_bf16(ah, b0, acc2[0], 0, 0, 0);
        acc2[0] = __builtin_amdgcn_mfma_f32_16x16x32_bf16(al, b0, acc2[0], 0, 0, 0);
        acc2[1] = __builtin_amdgcn_mfma_f32_16x16x32_bf16(ah, b1, acc2[1], 0, 0, 0);
        acc2[1] = __builtin_amdgcn_mfma_f32_16x16x32_bf16(al, b1, acc2[1], 0, 0, 0);
    }
    #pragma unroll
    for (int c = 0; c < 2; ++c) {
        int g = wave * 32 + c * 16 + m;
        float bh = bm1[g];
        #pragma unroll
        for (int r = 0; r < 4; ++r) {
            unsigned short hi, lo;
            bf_split(silu_f(acc2[c][r] + bh), hi, lo);
            HIh[quad * 4 + r][g] = hi;
            HIl[quad * 4 + r][g] = lo;
        }
    }
    __syncthreads();

    f32x4 acc3[3][2];
    #pragma unroll
    for (int o = 0; o < 3; ++o)
        #pragma unroll
        for (int c = 0; c < 2; ++c)
            acc3[o][c] = (f32x4){0.f, 0.f, 0.f, 0.f};
    const bf16x8* M2f = (const bf16x8*)M2s;
    #pragma unroll
    for (int kc = 0; kc < 4; ++kc) {
        bf16x8 ah = *(const bf16x8*)&HIh[m][kc * 32 + quad * 8];
        bf16x8 al = *(const bf16x8*)&HIl[m][kc * 32 + quad * 8];
        #pragma unroll
        for (int o = 0; o < 3; ++o)
            #pragma unroll
            for (int c = 0; c < 2; ++c) {
                bf16x8 bb = M2f[(((o * 8) + wave * 2 + c) * 4 + kc) * 64 + lane];
                acc3[o][c] = __builtin_amdgcn_mfma_f32_16x16x32_bf16(ah, bb, acc3[o][c], 0, 0, 0);
                acc3[o][c] = __builtin_amdgcn_mfma_f32_16x16x32_bf16(al, bb, acc3[o][c], 0, 0, 0);
            }
    }

    #pragma unroll
    for (int c = 0; c < 2; ++c) {
        int g = wave * 32 + c * 16 + m;
        float bvv = bm2[g], bsv = bm2[128 + g], bss = bm2[256 + g];
        #pragma unroll
        for (int r = 0; r < 4; ++r) {
            int nl = quad * 4 + r;
            int n = n0 + nl;
            float a_vv = acc3[0][c][r] + bvv;
            float a_sv = acc3[1][c][r] + bsv;
            float a_ss = acc3[2][c][r] + bss;
            float dotuv = accU[0][c][r] * accV[0][c][r] +
                          accU[1][c][r] * accV[1][c][r] +
                          accU[2][c][r] * accV[2][c][r];
            s_out[(size_t)n * F + g] =
                s_agg[(size_t)n * F + g] + dotuv * a_sv + a_ss;
            #pragma unroll
            for (int d = 0; d < 3; ++d)
                v_out[(size_t)n * F3 + g * 3 + d] =
                    v_agg[(size_t)n * F3 + g * 3 + d] + a_vv * accU[d][c][r];
        }
    }
}

// ---------------------------------------------------------------------------
extern "C" void kernel_launch(void* const* d_in, const int* in_sizes, int n_in,
                              void* d_out, int out_size, void* d_ws, size_t ws_size,
                              hipStream_t stream) {
    const float* s    = (const float*)d_in[0];
    const float* v    = (const float*)d_in[1];
    const float* rbf  = (const float*)d_in[2];
    const float* dir  = (const float*)d_in[3];
    const float* W1   = (const float*)d_in[4];
    const float* b1   = (const float*)d_in[5];
    const float* W2   = (const float*)d_in[6];
    const float* b2   = (const float*)d_in[7];
    const float* Wr   = (const float*)d_in[8];
    const float* br   = (const float*)d_in[9];
    const float* WU   = (const float*)d_in[10];
    const float* bU   = (const float*)d_in[11];
    const float* WV   = (const float*)d_in[12];
    const float* bV   = (const float*)d_in[13];
    const float* M1   = (const float*)d_in[14];
    const float* bm1  = (const float*)d_in[15];
    const float* M2   = (const float*)d_in[16];
    const float* bm2  = (const float*)d_in[17];
    const int* i_index = (const int*)d_in[18];
    const int* j_index = (const int*)d_in[19];

    float* out_s = (float*)d_out;                     // N*F
    float* out_v = out_s + (size_t)N_NODES * F;       // N*F*3

    // workspace layout
    float* h       = (float*)d_ws;                         // N*384 floats
    float* s_agg   = h + (size_t)N_NODES * F3;             // N*128
    float* v_agg   = s_agg + (size_t)N_NODES * F;          // N*384
    int*   counts  = (int*)(v_agg + (size_t)N_NODES * F3); // N
    int*   row_start = counts + N_NODES;                   // N+1
    int*   cursor  = row_start + N_NODES + 1;              // N
    int*   edge_ids = cursor + N_NODES;                    // E
    int*   chunk_sum = edge_ids + E_EDGES;                 // 128
    int*   chunk_off = chunk_sum + 128;                    // 128
    unsigned short* W1s = (unsigned short*)(chunk_off + 128);  // 8*4*64*8
    unsigned short* W2s = W1s + 8 * 4 * 64 * 8;                // 24*4*64*8
    unsigned short* WUVs = W2s + 24 * 4 * 64 * 8;              // 16*4*64*8
    unsigned short* M1s  = WUVs + 16 * 4 * 64 * 8;             // 8*8*64*8
    unsigned short* M2s  = M1s + 8 * 8 * 64 * 8;               // 24*4*64*8

    hipMemsetAsync(counts, 0, sizeof(int) * N_NODES, stream);

    w_swizzle_all<<<88, 256, 0, stream>>>(W1, W2, WU, WV, M1, M2,
                                          W1s, W2s, WUVs, M1s, M2s);
    node_mlp_mfma<<<(N_NODES + 63) / 64, 256, 0, stream>>>(s, b1, b2, W1s, W2s, h);

    hist_kernel<<<(E_EDGES + 255) / 256, 256, 0, stream>>>(i_index, counts);
    scan_p1<<<NCHUNK, 256, 0, stream>>>(counts, row_start, chunk_sum);
    scan_p2<<<1, 128, 0, stream>>>(chunk_sum, chunk_off);
    scan_p3<<<NCHUNK, 256, 0, stream>>>(row_start, chunk_off, cursor);
    scatter_kernel<<<(E_EDGES + 255) / 256, 256, 0, stream>>>(i_index, cursor, edge_ids);

    agg_kernel<<<N_NODES / 2, 256, 0, stream>>>(s, v, rbf, dir, j_index, Wr, br, h,
                                                row_start, edge_ids, s_agg, v_agg);

    update_mfma<<<N_NODES / UB, 256, 0, stream>>>(s_agg, v_agg, WUVs, bU, bV,
                                                  M1s, bm1, M2s, bm2, out_s, out_v);
}

// Round 4
// 444.058 us; speedup vs baseline: 2.5207x; 1.1349x over previous
//
#include <hip/hip_runtime.h>
#include <hip/hip_bf16.h>
#include <math.h>

#define N_NODES 20000
#define F 128
#define NRBF 20
#define E_EDGES 320000
#define F3 (3 * F)   // 384
#define NCHUNK ((N_NODES + 255) / 256)   // 79

typedef __attribute__((ext_vector_type(8))) short bf16x8;
typedef __attribute__((ext_vector_type(4))) float f32x4;

__device__ __forceinline__ float silu_f(float x) {
    return x / (1.0f + __expf(-x));
}
__device__ __forceinline__ unsigned short bf_bits(float x) {
    __hip_bfloat16 b = __float2bfloat16(x);
    return *(unsigned short*)&b;
}
// split x into bf16 hi + bf16 lo (x ~ hi + lo, ~15-bit effective mantissa)
__device__ __forceinline__ void bf_split(float x, unsigned short& hi, unsigned short& lo) {
    __hip_bfloat16 h = __float2bfloat16(x);
    float hf = __bfloat162float(h);
    __hip_bfloat16 l = __float2bfloat16(x - hf);
    hi = *(unsigned short*)&h;
    lo = *(unsigned short*)&l;
}

// ---------------------------------------------------------------------------
// Merged weight pre-swizzle (node MLP W1/W2 + update MLP WUV/M1/M2).
//   element(lane,j) = W[k = kc*32 + (lane>>4)*8 + j][n = ct*16 + (lane&15)]
// ---------------------------------------------------------------------------
__global__ __launch_bounds__(256) void w_swizzle_all(
    const float* __restrict__ W1, const float* __restrict__ W2,
    const float* __restrict__ WU, const float* __restrict__ WV,
    const float* __restrict__ M1, const float* __restrict__ M2,
    unsigned short* __restrict__ W1s, unsigned short* __restrict__ W2s,
    unsigned short* __restrict__ WUVs, unsigned short* __restrict__ M1s,
    unsigned short* __restrict__ M2s)
{
    int tid = blockIdx.x * 256 + threadIdx.x;
    if (tid < 8 * 4 * 64) {                                // W1
        int lane = tid & 63, kc = (tid >> 6) & 3, ct = tid >> 8;
        int n = ct * 16 + (lane & 15);
        int k0 = kc * 32 + (lane >> 4) * 8;
        #pragma unroll
        for (int j = 0; j < 8; ++j)
            W1s[tid * 8 + j] = bf_bits(W1[(k0 + j) * F + n]);
    } else if (tid < 8 * 4 * 64 + 24 * 4 * 64) {           // W2
        int t = tid - 8 * 4 * 64;
        int lane = t & 63, kc = (t >> 6) & 3, ct = t >> 8;
        int n = ct * 16 + (lane & 15);
        int k0 = kc * 32 + (lane >> 4) * 8;
        #pragma unroll
        for (int j = 0; j < 8; ++j)
            W2s[t * 8 + j] = bf_bits(W2[(k0 + j) * F3 + n]);
    } else if (tid < 8192 + 224 * 64) {                    // update-MLP weights
        int t2 = tid - 8192;
        int lane = t2 & 63;
        int set = t2 >> 6;
        if (set < 64) {                       // WUV: frag idx (ct*4+kc)
            int kc = set & 3, ct = set >> 2;
            int n = ct * 16 + (lane & 15);
            int k0 = kc * 32 + (lane >> 4) * 8;
            const float* W = (ct < 8) ? WU : WV;
            int nn = n & 127;
            #pragma unroll
            for (int j = 0; j < 8; ++j)
                WUVs[(size_t)(set * 64 + lane) * 8 + j] = bf_bits(W[(k0 + j) * F + nn]);
        } else if (set < 128) {               // M1: frag idx (ct*8+kc)
            int t = set - 64;
            int kc = t & 7, ct = t >> 3;
            int n = ct * 16 + (lane & 15);
            int k0 = kc * 32 + (lane >> 4) * 8;
            #pragma unroll
            for (int j = 0; j < 8; ++j)
                M1s[(size_t)(t * 64 + lane) * 8 + j] = bf_bits(M1[(k0 + j) * F + n]);
        } else {                              // M2: frag idx (ct*4+kc)
            int t = set - 128;
            int kc = t & 3, ct = t >> 2;
            int n = ct * 16 + (lane & 15);
            int k0 = kc * 32 + (lane >> 4) * 8;
            #pragma unroll
            for (int j = 0; j < 8; ++j)
                M2s[(size_t)(t * 64 + lane) * 8 + j] = bf_bits(M2[(k0 + j) * F3 + n]);
        }
    }
}

// ---------------------------------------------------------------------------
// Kernel A (MFMA): h = silu(s@W1+b1)@W2 + b2, bf16 inputs / fp32 accum.
// ---------------------------------------------------------------------------
#define SLD 136   // padded row stride (elements) for LDS tiles
__global__ __launch_bounds__(256) void node_mlp_mfma(
    const float* __restrict__ s, const float* __restrict__ b1,
    const float* __restrict__ b2,
    const unsigned short* __restrict__ W1s, const unsigned short* __restrict__ W2s,
    float* __restrict__ h)
{
    __shared__ unsigned short Sl[64][SLD];        // 17408 B
    __shared__ unsigned short Hid[4][16][SLD];    // 17408 B

    const int tid = threadIdx.x;
    const int lane = tid & 63, wave = tid >> 6;
    const int m = lane & 15, quad = lane >> 4;
    const int n0 = blockIdx.x * 64;

    for (int i = tid; i < 64 * F; i += 256) {
        int r = i >> 7, c = i & 127;
        int nn = n0 + r;
        if (nn >= N_NODES) nn = N_NODES - 1;
        Sl[r][c] = bf_bits(s[(size_t)nn * F + c]);
    }
    __syncthreads();

    const int arow = wave * 16 + m;
    bf16x8 a1[4];
    #pragma unroll
    for (int kc = 0; kc < 4; ++kc)
        a1[kc] = *(const bf16x8*)&Sl[arow][kc * 32 + quad * 8];

    const bf16x8* W1f = (const bf16x8*)W1s;
    #pragma unroll
    for (int ct = 0; ct < 8; ++ct) {
        f32x4 acc = {0.f, 0.f, 0.f, 0.f};
        #pragma unroll
        for (int kc = 0; kc < 4; ++kc)
            acc = __builtin_amdgcn_mfma_f32_16x16x32_bf16(
                a1[kc], W1f[(ct * 4 + kc) * 64 + lane], acc, 0, 0, 0);
        float bias = b1[ct * 16 + m];
        #pragma unroll
        for (int r = 0; r < 4; ++r)
            Hid[wave][quad * 4 + r][ct * 16 + m] = bf_bits(silu_f(acc[r] + bias));
    }
    __syncthreads();

    bf16x8 a2[4];
    #pragma unroll
    for (int kc = 0; kc < 4; ++kc)
        a2[kc] = *(const bf16x8*)&Hid[wave][m][kc * 32 + quad * 8];

    const bf16x8* W2f = (const bf16x8*)W2s;
    #pragma unroll
    for (int ct = 0; ct < 24; ++ct) {
        f32x4 acc = {0.f, 0.f, 0.f, 0.f};
        #pragma unroll
        for (int kc = 0; kc < 4; ++kc)
            acc = __builtin_amdgcn_mfma_f32_16x16x32_bf16(
                a2[kc], W2f[(ct * 4 + kc) * 64 + lane], acc, 0, 0, 0);
        float bias = b2[ct * 16 + m];
        #pragma unroll
        for (int r = 0; r < 4; ++r) {
            int node = n0 + wave * 16 + quad * 4 + r;
            if (node < N_NODES)
                h[(size_t)node * F3 + ct * 16 + m] = acc[r] + bias;
        }
    }
}

// ---------------------------------------------------------------------------
// CSR build: histogram -> 3-phase parallel scan -> scatter.
// scatter additionally materializes edge_j[pos] = j_index[e] so agg has no
// dependent e->j load.
// ---------------------------------------------------------------------------
__global__ __launch_bounds__(256) void hist_kernel(const int* __restrict__ i_index,
                                                   int* __restrict__ counts)
{
    int e = blockIdx.x * 256 + threadIdx.x;
    if (e < E_EDGES) atomicAdd(&counts[i_index[e]], 1);
}

__global__ __launch_bounds__(256) void scan_p1(const int* __restrict__ counts,
                                               int* __restrict__ row_start,
                                               int* __restrict__ chunk_sum)
{
    __shared__ int buf[256];
    const int tid = threadIdx.x;
    const int idx = blockIdx.x * 256 + tid;
    int val = (idx < N_NODES) ? counts[idx] : 0;
    buf[tid] = val;
    __syncthreads();
    for (int off = 1; off < 256; off <<= 1) {
        int t = (tid >= off) ? buf[tid - off] : 0;
        __syncthreads();
        buf[tid] += t;
        __syncthreads();
    }
    if (idx < N_NODES) row_start[idx] = buf[tid] - val;
    if (tid == 255) chunk_sum[blockIdx.x] = buf[255];
}

__global__ __launch_bounds__(128) void scan_p2(const int* __restrict__ chunk_sum,
                                               int* __restrict__ chunk_off)
{
    __shared__ int buf[128];
    const int tid = threadIdx.x;
    int val = (tid < NCHUNK) ? chunk_sum[tid] : 0;
    buf[tid] = val;
    __syncthreads();
    for (int off = 1; off < 128; off <<= 1) {
        int t = (tid >= off) ? buf[tid - off] : 0;
        __syncthreads();
        buf[tid] += t;
        __syncthreads();
    }
    if (tid < NCHUNK) chunk_off[tid] = buf[tid] - val;
}

__global__ __launch_bounds__(256) void scan_p3(int* __restrict__ row_start,
                                               const int* __restrict__ chunk_off,
                                               int* __restrict__ cursor)
{
    int idx = blockIdx.x * 256 + threadIdx.x;
    if (idx < N_NODES) {
        int vv = row_start[idx] + chunk_off[blockIdx.x];
        row_start[idx] = vv;
        cursor[idx] = vv;
    }
    if (idx == 0) row_start[N_NODES] = E_EDGES;
}

__global__ __launch_bounds__(256) void scatter_kernel(const int* __restrict__ i_index,
                                                      const int* __restrict__ j_index,
                                                      int* __restrict__ cursor,
                                                      int* __restrict__ edge_ids,
                                                      int* __restrict__ edge_j)
{
    int e = blockIdx.x * 256 + threadIdx.x;
    if (e < E_EDGES) {
        int j = j_index[e];
        int pos = atomicAdd(&cursor[i_index[e]], 1);
        edge_ids[pos] = e;
        edge_j[pos] = j;
    }
}

// ---------------------------------------------------------------------------
// Kernel B: per-destination-node aggregation.
// R1 structure (128 thr, n = blockIdx.x => e/j/rbf/dir wave-uniform ->
// SGPR s_loads) + 1-deep software pipeline: all of edge k+1's loads issue
// before edge k's compute. Uniform state (e,j,rbf row,dir) lives in SGPRs;
// only the 6 per-lane h/v gathers add VGPR state (+6).
// Accumulation order identical to R1 -> bit-identical numerics.
// ---------------------------------------------------------------------------
__global__ __launch_bounds__(128) void agg_kernel(
    const float* __restrict__ s, const float* __restrict__ v,
    const float* __restrict__ rbf, const float* __restrict__ dir,
    const float* __restrict__ Wr, const float* __restrict__ br,
    const float* __restrict__ h,
    const int* __restrict__ row_start, const int* __restrict__ edge_ids,
    const int* __restrict__ edge_j,
    float* __restrict__ s_agg, float* __restrict__ v_agg)
{
    const int f = threadIdx.x;
    const int n = blockIdx.x;

    float wr0[NRBF], wr1[NRBF], wr2[NRBF];
    #pragma unroll
    for (int k = 0; k < NRBF; ++k) {
        wr0[k] = Wr[k * F3 + f];
        wr1[k] = Wr[k * F3 + F + f];
        wr2[k] = Wr[k * F3 + 2 * F + f];
    }
    const float br0 = br[f], br1 = br[F + f], br2 = br[2 * F + f];

    float s_acc = s[n * F + f];
    float v0 = v[n * F3 + f * 3 + 0];
    float v1 = v[n * F3 + f * 3 + 1];
    float v2 = v[n * F3 + f * 3 + 2];

    const int beg = row_start[n];
    const int end = row_start[n + 1];
    const float cc = 0.6283185307179586f;   // pi/5

    // pipeline state for the "current" edge
    float rC[NRBF];
    float dCx = 0.f, dCy = 0.f, dCz = 0.f;
    float hCs = 0.f, hCvs = 0.f, hCvv = 0.f;
    float vC0 = 0.f, vC1 = 0.f, vC2 = 0.f;

    if (beg < end) {
        int e0 = edge_ids[beg];
        int j0 = edge_j[beg];
        #pragma unroll
        for (int k = 0; k < NRBF; ++k) rC[k] = rbf[e0 * NRBF + k];
        dCx = dir[e0 * 3 + 0]; dCy = dir[e0 * 3 + 1]; dCz = dir[e0 * 3 + 2];
        hCs  = h[j0 * F3 + f];
        hCvs = h[j0 * F3 + F + f];
        hCvv = h[j0 * F3 + 2 * F + f];
        vC0 = v[j0 * F3 + f * 3 + 0];
        vC1 = v[j0 * F3 + f * 3 + 1];
        vC2 = v[j0 * F3 + f * 3 + 2];
    }

    for (int idx = beg; idx < end; ++idx) {
        // ---- prefetch edge idx+1 (clamped; last iter harmlessly reloads) ----
        const int ip = (idx + 1 < end) ? idx + 1 : idx;
        const int eN = edge_ids[ip];
        const int jN = edge_j[ip];
        float rN[NRBF];
        #pragma unroll
        for (int k = 0; k < NRBF; ++k) rN[k] = rbf[eN * NRBF + k];
        const float dNx = dir[eN * 3 + 0];
        const float dNy = dir[eN * 3 + 1];
        const float dNz = dir[eN * 3 + 2];
        const float hNs  = h[jN * F3 + f];
        const float hNvs = h[jN * F3 + F + f];
        const float hNvv = h[jN * F3 + 2 * F + f];
        const float vN0 = v[jN * F3 + f * 3 + 0];
        const float vN1 = v[jN * F3 + f * 3 + 1];
        const float vN2 = v[jN * F3 + f * 3 + 2];

        // ---- compute current edge ----
        float x0 = br0, x1 = br1, x2 = br2;
        #pragma unroll
        for (int k = 0; k < NRBF; ++k) {
            x0 += rC[k] * wr0[k];
            x1 += rC[k] * wr1[k];
            x2 += rC[k] * wr2[k];
        }
        float w0 = (x0 < 5.0f) ? 0.5f * (__cosf(x0 * cc) + 1.0f) : 0.0f;
        float w1 = (x1 < 5.0f) ? 0.5f * (__cosf(x1 * cc) + 1.0f) : 0.0f;
        float w2 = (x2 < 5.0f) ? 0.5f * (__cosf(x2 * cc) + 1.0f) : 0.0f;

        s_acc += hCs * w0;
        float g = hCvs * w1, u = hCvv * w2;
        v0 += g * dCx + u * vC0;
        v1 += g * dCy + u * vC1;
        v2 += g * dCz + u * vC2;

        // ---- rotate pipeline ----
        #pragma unroll
        for (int k = 0; k < NRBF; ++k) rC[k] = rN[k];
        dCx = dNx; dCy = dNy; dCz = dNz;
        hCs = hNs; hCvs = hNvs; hCvv = hNvv;
        vC0 = vN0; vC1 = vN1; vC2 = vN2;
    }

    s_agg[n * F + f] = s_acc;
    v_agg[n * F3 + f * 3 + 0] = v0;
    v_agg[n * F3 + f * 3 + 1] = v1;
    v_agg[n * F3 + f * 3 + 2] = v2;
}

// ---------------------------------------------------------------------------
// Kernel C: per-node update via MFMA (unchanged).
// ---------------------------------------------------------------------------
#define UB 16
__global__ __launch_bounds__(256) void update_mfma(
    const float* __restrict__ s_agg, const float* __restrict__ v_agg,
    const unsigned short* __restrict__ WUVs,
    const float* __restrict__ bU, const float* __restrict__ bV,
    const unsigned short* __restrict__ M1s, const float* __restrict__ bm1,
    const unsigned short* __restrict__ M2s, const float* __restrict__ bm2,
    float* __restrict__ s_out, float* __restrict__ v_out)
{
    __shared__ unsigned short VAh[48][SLD],  VAl[48][SLD];
    __shared__ unsigned short MIh[16][264],  MIl[16][264];
    __shared__ unsigned short HIh[16][SLD],  HIl[16][SLD];

    const int tid = threadIdx.x;
    const int lane = tid & 63, wave = tid >> 6;
    const int m = lane & 15, quad = lane >> 4;
    const int n0 = blockIdx.x * UB;

    for (int i = tid; i < UB * F3; i += 256) {
        int nl = i / F3, r = i - nl * F3;
        int f = r / 3, d = r - f * 3;
        unsigned short hi, lo;
        bf_split(v_agg[(size_t)n0 * F3 + i], hi, lo);
        VAh[d * 16 + nl][f] = hi;
        VAl[d * 16 + nl][f] = lo;
    }
    __syncthreads();

    f32x4 accU[3][2], accV[3][2];
    #pragma unroll
    for (int d = 0; d < 3; ++d)
        #pragma unroll
        for (int c = 0; c < 2; ++c) {
            accU[d][c] = (f32x4){0.f, 0.f, 0.f, 0.f};
            accV[d][c] = (f32x4){0.f, 0.f, 0.f, 0.f};
        }

    const bf16x8* Wf  = (const bf16x8*)WUVs;
    #pragma unroll
    for (int kc = 0; kc < 4; ++kc) {
        bf16x8 bu0 = Wf[((wave * 2 + 0) * 4 + kc) * 64 + lane];
        bf16x8 bu1 = Wf[((wave * 2 + 1) * 4 + kc) * 64 + lane];
        bf16x8 bv0 = Wf[((8 + wave * 2 + 0) * 4 + kc) * 64 + lane];
        bf16x8 bv1 = Wf[((8 + wave * 2 + 1) * 4 + kc) * 64 + lane];
        #pragma unroll
        for (int d = 0; d < 3; ++d) {
            bf16x8 ah = *(const bf16x8*)&VAh[d * 16 + m][kc * 32 + quad * 8];
            bf16x8 al = *(const bf16x8*)&VAl[d * 16 + m][kc * 32 + quad * 8];
            accU[d][0] = __builtin_amdgcn_mfma_f32_16x16x32_bf16(ah, bu0, accU[d][0], 0, 0, 0);
            accU[d][0] = __builtin_amdgcn_mfma_f32_16x16x32_bf16(al, bu0, accU[d][0], 0, 0, 0);
            accU[d][1] = __builtin_amdgcn_mfma_f32_16x16x32_bf16(ah, bu1, accU[d][1], 0, 0, 0);
            accU[d][1] = __builtin_amdgcn_mfma_f32_16x16x32_bf16(al, bu1, accU[d][1], 0, 0, 0);
            accV[d][0] = __builtin_amdgcn_mfma_f32_16x16x32_bf16(ah, bv0, accV[d][0], 0, 0, 0);
            accV[d][0] = __builtin_amdgcn_mfma_f32_16x16x32_bf16(al, bv0, accV[d][0], 0, 0, 0);
            accV[d][1] = __builtin_amdgcn_mfma_f32_16x16x32_bf16(ah, bv1, accV[d][1], 0, 0, 0);
            accV[d][1] = __builtin_amdgcn_mfma_f32_16x16x32_bf16(al, bv1, accV[d][1], 0, 0, 0);
        }
    }

    #pragma unroll
    for (int c = 0; c < 2; ++c) {
        int g = wave * 32 + c * 16 + m;
        float bu = bU[g], bv = bV[g];
        #pragma unroll
        for (int d = 0; d < 3; ++d)
            #pragma unroll
            for (int r = 0; r < 4; ++r) {
                accU[d][c][r] += bu;
                accV[d][c][r] += bv;
            }
        #pragma unroll
        for (int r = 0; r < 4; ++r) {
            int nl = quad * 4 + r;
            float nv = sqrtf(accV[0][c][r] * accV[0][c][r] +
                             accV[1][c][r] * accV[1][c][r] +
                             accV[2][c][r] * accV[2][c][r]);
            unsigned short hi, lo;
            bf_split(nv, hi, lo);
            MIh[nl][g] = hi; MIl[nl][g] = lo;
            bf_split(s_agg[(size_t)(n0 + nl) * F + g], hi, lo);
            MIh[nl][128 + g] = hi; MIl[nl][128 + g] = lo;
        }
    }
    __syncthreads();

    f32x4 acc2[2];
    acc2[0] = (f32x4){0.f, 0.f, 0.f, 0.f};
    acc2[1] = (f32x4){0.f, 0.f, 0.f, 0.f};
    const bf16x8* M1f = (const bf16x8*)M1s;
    #pragma unroll
    for (int kc = 0; kc < 8; ++kc) {
        bf16x8 ah = *(const bf16x8*)&MIh[m][kc * 32 + quad * 8];
        bf16x8 al = *(const bf16x8*)&MIl[m][kc * 32 + quad * 8];
        bf16x8 b0 = M1f[((wave * 2 + 0) * 8 + kc) * 64 + lane];
        bf16x8 b1 = M1f[((wave * 2 + 1) * 8 + kc) * 64 + lane];
        acc2[0] = __builtin_amdgcn_mfma_f32_16x16x32_bf16(ah, b0, acc2[0], 0, 0, 0);
        acc2[0] = __builtin_amdgcn_mfma_f32_16x16x32_bf16(al, b0, acc2[0], 0, 0, 0);
        acc2[1] = __builtin_amdgcn_mfma_f32_16x16x32_bf16(ah, b1, acc2[1], 0, 0, 0);
        acc2[1] = __builtin_amdgcn_mfma_f32_16x16x32_bf16(al, b1, acc2[1], 0, 0, 0);
    }
    #pragma unroll
    for (int c = 0; c < 2; ++c) {
        int g = wave * 32 + c * 16 + m;
        float bh = bm1[g];
        #pragma unroll
        for (int r = 0; r < 4; ++r) {
            unsigned short hi, lo;
            bf_split(silu_f(acc2[c][r] + bh), hi, lo);
            HIh[quad * 4 + r][g] = hi;
            HIl[quad * 4 + r][g] = lo;
        }
    }
    __syncthreads();

    f32x4 acc3[3][2];
    #pragma unroll
    for (int o = 0; o < 3; ++o)
        #pragma unroll
        for (int c = 0; c < 2; ++c)
            acc3[o][c] = (f32x4){0.f, 0.f, 0.f, 0.f};
    const bf16x8* M2f = (const bf16x8*)M2s;
    #pragma unroll
    for (int kc = 0; kc < 4; ++kc) {
        bf16x8 ah = *(const bf16x8*)&HIh[m][kc * 32 + quad * 8];
        bf16x8 al = *(const bf16x8*)&HIl[m][kc * 32 + quad * 8];
        #pragma unroll
        for (int o = 0; o < 3; ++o)
            #pragma unroll
            for (int c = 0; c < 2; ++c) {
                bf16x8 bb = M2f[(((o * 8) + wave * 2 + c) * 4 + kc) * 64 + lane];
                acc3[o][c] = __builtin_amdgcn_mfma_f32_16x16x32_bf16(ah, bb, acc3[o][c], 0, 0, 0);
                acc3[o][c] = __builtin_amdgcn_mfma_f32_16x16x32_bf16(al, bb, acc3[o][c], 0, 0, 0);
            }
    }

    #pragma unroll
    for (int c = 0; c < 2; ++c) {
        int g = wave * 32 + c * 16 + m;
        float bvv = bm2[g], bsv = bm2[128 + g], bss = bm2[256 + g];
        #pragma unroll
        for (int r = 0; r < 4; ++r) {
            int nl = quad * 4 + r;
            int n = n0 + nl;
            float a_vv = acc3[0][c][r] + bvv;
            float a_sv = acc3[1][c][r] + bsv;
            float a_ss = acc3[2][c][r] + bss;
            float dotuv = accU[0][c][r] * accV[0][c][r] +
                          accU[1][c][r] * accV[1][c][r] +
                          accU[2][c][r] * accV[2][c][r];
            s_out[(size_t)n * F + g] =
                s_agg[(size_t)n * F + g] + dotuv * a_sv + a_ss;
            #pragma unroll
            for (int d = 0; d < 3; ++d)
                v_out[(size_t)n * F3 + g * 3 + d] =
                    v_agg[(size_t)n * F3 + g * 3 + d] + a_vv * accU[d][c][r];
        }
    }
}

// ---------------------------------------------------------------------------
extern "C" void kernel_launch(void* const* d_in, const int* in_sizes, int n_in,
                              void* d_out, int out_size, void* d_ws, size_t ws_size,
                              hipStream_t stream) {
    const float* s    = (const float*)d_in[0];
    const float* v    = (const float*)d_in[1];
    const float* rbf  = (const float*)d_in[2];
    const float* dir  = (const float*)d_in[3];
    const float* W1   = (const float*)d_in[4];
    const float* b1   = (const float*)d_in[5];
    const float* W2   = (const float*)d_in[6];
    const float* b2   = (const float*)d_in[7];
    const float* Wr   = (const float*)d_in[8];
    const float* br   = (const float*)d_in[9];
    const float* WU   = (const float*)d_in[10];
    const float* bU   = (const float*)d_in[11];
    const float* WV   = (const float*)d_in[12];
    const float* bV   = (const float*)d_in[13];
    const float* M1   = (const float*)d_in[14];
    const float* bm1  = (const float*)d_in[15];
    const float* M2   = (const float*)d_in[16];
    const float* bm2  = (const float*)d_in[17];
    const int* i_index = (const int*)d_in[18];
    const int* j_index = (const int*)d_in[19];

    float* out_s = (float*)d_out;                     // N*F
    float* out_v = out_s + (size_t)N_NODES * F;       // N*F*3

    // workspace layout
    float* h       = (float*)d_ws;                         // N*384 floats
    float* s_agg   = h + (size_t)N_NODES * F3;             // N*128
    float* v_agg   = s_agg + (size_t)N_NODES * F;          // N*384
    int*   counts  = (int*)(v_agg + (size_t)N_NODES * F3); // N
    int*   row_start = counts + N_NODES;                   // N+1
    int*   cursor  = row_start + N_NODES + 1;              // N
    int*   edge_ids = cursor + N_NODES;                    // E
    int*   edge_j  = edge_ids + E_EDGES;                   // E
    int*   chunk_sum = edge_j + E_EDGES;                   // 128
    int*   chunk_off = chunk_sum + 128;                    // 128
    unsigned short* W1s = (unsigned short*)(chunk_off + 128);  // 8*4*64*8
    unsigned short* W2s = W1s + 8 * 4 * 64 * 8;                // 24*4*64*8
    unsigned short* WUVs = W2s + 24 * 4 * 64 * 8;              // 16*4*64*8
    unsigned short* M1s  = WUVs + 16 * 4 * 64 * 8;             // 8*8*64*8
    unsigned short* M2s  = M1s + 8 * 8 * 64 * 8;               // 24*4*64*8

    hipMemsetAsync(counts, 0, sizeof(int) * N_NODES, stream);

    w_swizzle_all<<<88, 256, 0, stream>>>(W1, W2, WU, WV, M1, M2,
                                          W1s, W2s, WUVs, M1s, M2s);
    node_mlp_mfma<<<(N_NODES + 63) / 64, 256, 0, stream>>>(s, b1, b2, W1s, W2s, h);

    hist_kernel<<<(E_EDGES + 255) / 256, 256, 0, stream>>>(i_index, counts);
    scan_p1<<<NCHUNK, 256, 0, stream>>>(counts, row_start, chunk_sum);
    scan_p2<<<1, 128, 0, stream>>>(chunk_sum, chunk_off);
    scan_p3<<<NCHUNK, 256, 0, stream>>>(row_start, chunk_off, cursor);
    scatter_kernel<<<(E_EDGES + 255) / 256, 256, 0, stream>>>(i_index, j_index,
                                                              cursor, edge_ids, edge_j);

    agg_kernel<<<N_NODES, 128, 0, stream>>>(s, v, rbf, dir, Wr, br, h,
                                            row_start, edge_ids, edge_j,
                                            s_agg, v_agg);

    update_mfma<<<N_NODES / UB, 256, 0, stream>>>(s_agg, v_agg, WUVs, bU, bV,
                                                  M1s, bm1, M2s, bm2, out_s, out_v);
}

// Round 5
// 405.957 us; speedup vs baseline: 2.7572x; 1.0939x over previous
//
#include <hip/hip_runtime.h>
#include <hip/hip_bf16.h>
#include <math.h>

#define N_NODES 20000
#define F 128
#define NRBF 20
#define E_EDGES 320000
#define F3 (3 * F)   // 384
#define NCHUNK ((N_NODES + 255) / 256)   // 79

typedef __attribute__((ext_vector_type(8))) short bf16x8;
typedef __attribute__((ext_vector_type(4))) float f32x4;

__device__ __forceinline__ float silu_f(float x) {
    return x / (1.0f + __expf(-x));
}
__device__ __forceinline__ unsigned short bf_bits(float x) {
    __hip_bfloat16 b = __float2bfloat16(x);
    return *(unsigned short*)&b;
}
// split x into bf16 hi + bf16 lo (x ~ hi + lo, ~15-bit effective mantissa)
__device__ __forceinline__ void bf_split(float x, unsigned short& hi, unsigned short& lo) {
    __hip_bfloat16 h = __float2bfloat16(x);
    float hf = __bfloat162float(h);
    __hip_bfloat16 l = __float2bfloat16(x - hf);
    hi = *(unsigned short*)&h;
    lo = *(unsigned short*)&l;
}

// ---------------------------------------------------------------------------
// Merged weight pre-swizzle (node MLP W1/W2 + update MLP WUV/M1/M2).
//   element(lane,j) = W[k = kc*32 + (lane>>4)*8 + j][n = ct*16 + (lane&15)]
// ---------------------------------------------------------------------------
__global__ __launch_bounds__(256) void w_swizzle_all(
    const float* __restrict__ W1, const float* __restrict__ W2,
    const float* __restrict__ WU, const float* __restrict__ WV,
    const float* __restrict__ M1, const float* __restrict__ M2,
    unsigned short* __restrict__ W1s, unsigned short* __restrict__ W2s,
    unsigned short* __restrict__ WUVs, unsigned short* __restrict__ M1s,
    unsigned short* __restrict__ M2s)
{
    int tid = blockIdx.x * 256 + threadIdx.x;
    if (tid < 8 * 4 * 64) {                                // W1
        int lane = tid & 63, kc = (tid >> 6) & 3, ct = tid >> 8;
        int n = ct * 16 + (lane & 15);
        int k0 = kc * 32 + (lane >> 4) * 8;
        #pragma unroll
        for (int j = 0; j < 8; ++j)
            W1s[tid * 8 + j] = bf_bits(W1[(k0 + j) * F + n]);
    } else if (tid < 8 * 4 * 64 + 24 * 4 * 64) {           // W2
        int t = tid - 8 * 4 * 64;
        int lane = t & 63, kc = (t >> 6) & 3, ct = t >> 8;
        int n = ct * 16 + (lane & 15);
        int k0 = kc * 32 + (lane >> 4) * 8;
        #pragma unroll
        for (int j = 0; j < 8; ++j)
            W2s[t * 8 + j] = bf_bits(W2[(k0 + j) * F3 + n]);
    } else if (tid < 8192 + 224 * 64) {                    // update-MLP weights
        int t2 = tid - 8192;
        int lane = t2 & 63;
        int set = t2 >> 6;
        if (set < 64) {                       // WUV: frag idx (ct*4+kc)
            int kc = set & 3, ct = set >> 2;
            int n = ct * 16 + (lane & 15);
            int k0 = kc * 32 + (lane >> 4) * 8;
            const float* W = (ct < 8) ? WU : WV;
            int nn = n & 127;
            #pragma unroll
            for (int j = 0; j < 8; ++j)
                WUVs[(size_t)(set * 64 + lane) * 8 + j] = bf_bits(W[(k0 + j) * F + nn]);
        } else if (set < 128) {               // M1: frag idx (ct*8+kc)
            int t = set - 64;
            int kc = t & 7, ct = t >> 3;
            int n = ct * 16 + (lane & 15);
            int k0 = kc * 32 + (lane >> 4) * 8;
            #pragma unroll
            for (int j = 0; j < 8; ++j)
                M1s[(size_t)(t * 64 + lane) * 8 + j] = bf_bits(M1[(k0 + j) * F + n]);
        } else {                              // M2: frag idx (ct*4+kc)
            int t = set - 128;
            int kc = t & 3, ct = t >> 2;
            int n = ct * 16 + (lane & 15);
            int k0 = kc * 32 + (lane >> 4) * 8;
            #pragma unroll
            for (int j = 0; j < 8; ++j)
                M2s[(size_t)(t * 64 + lane) * 8 + j] = bf_bits(M2[(k0 + j) * F3 + n]);
        }
    }
}

// ---------------------------------------------------------------------------
// Kernel A (MFMA): h = silu(s@W1+b1)@W2 + b2, bf16 inputs / fp32 accum.
// ---------------------------------------------------------------------------
#define SLD 136   // padded row stride (elements) for LDS tiles
__global__ __launch_bounds__(256) void node_mlp_mfma(
    const float* __restrict__ s, const float* __restrict__ b1,
    const float* __restrict__ b2,
    const unsigned short* __restrict__ W1s, const unsigned short* __restrict__ W2s,
    float* __restrict__ h)
{
    __shared__ unsigned short Sl[64][SLD];        // 17408 B
    __shared__ unsigned short Hid[4][16][SLD];    // 17408 B

    const int tid = threadIdx.x;
    const int lane = tid & 63, wave = tid >> 6;
    const int m = lane & 15, quad = lane >> 4;
    const int n0 = blockIdx.x * 64;

    for (int i = tid; i < 64 * F; i += 256) {
        int r = i >> 7, c = i & 127;
        int nn = n0 + r;
        if (nn >= N_NODES) nn = N_NODES - 1;
        Sl[r][c] = bf_bits(s[(size_t)nn * F + c]);
    }
    __syncthreads();

    const int arow = wave * 16 + m;
    bf16x8 a1[4];
    #pragma unroll
    for (int kc = 0; kc < 4; ++kc)
        a1[kc] = *(const bf16x8*)&Sl[arow][kc * 32 + quad * 8];

    const bf16x8* W1f = (const bf16x8*)W1s;
    #pragma unroll
    for (int ct = 0; ct < 8; ++ct) {
        f32x4 acc = {0.f, 0.f, 0.f, 0.f};
        #pragma unroll
        for (int kc = 0; kc < 4; ++kc)
            acc = __builtin_amdgcn_mfma_f32_16x16x32_bf16(
                a1[kc], W1f[(ct * 4 + kc) * 64 + lane], acc, 0, 0, 0);
        float bias = b1[ct * 16 + m];
        #pragma unroll
        for (int r = 0; r < 4; ++r)
            Hid[wave][quad * 4 + r][ct * 16 + m] = bf_bits(silu_f(acc[r] + bias));
    }
    __syncthreads();

    bf16x8 a2[4];
    #pragma unroll
    for (int kc = 0; kc < 4; ++kc)
        a2[kc] = *(const bf16x8*)&Hid[wave][m][kc * 32 + quad * 8];

    const bf16x8* W2f = (const bf16x8*)W2s;
    #pragma unroll
    for (int ct = 0; ct < 24; ++ct) {
        f32x4 acc = {0.f, 0.f, 0.f, 0.f};
        #pragma unroll
        for (int kc = 0; kc < 4; ++kc)
            acc = __builtin_amdgcn_mfma_f32_16x16x32_bf16(
                a2[kc], W2f[(ct * 4 + kc) * 64 + lane], acc, 0, 0, 0);
        float bias = b2[ct * 16 + m];
        #pragma unroll
        for (int r = 0; r < 4; ++r) {
            int node = n0 + wave * 16 + quad * 4 + r;
            if (node < N_NODES)
                h[(size_t)node * F3 + ct * 16 + m] = acc[r] + bias;
        }
    }
}

// ---------------------------------------------------------------------------
// CSR build: histogram -> 3-phase parallel scan -> scatter.
// scatter materializes edge_j[pos] (no e->j load in agg) and edge_dir4[pos]
// (dir re-ordered into CSR order -> sequential uniform loads in agg).
// ---------------------------------------------------------------------------
__global__ __launch_bounds__(256) void hist_kernel(const int* __restrict__ i_index,
                                                   int* __restrict__ counts)
{
    int e = blockIdx.x * 256 + threadIdx.x;
    if (e < E_EDGES) atomicAdd(&counts[i_index[e]], 1);
}

__global__ __launch_bounds__(256) void scan_p1(const int* __restrict__ counts,
                                               int* __restrict__ row_start,
                                               int* __restrict__ chunk_sum)
{
    __shared__ int buf[256];
    const int tid = threadIdx.x;
    const int idx = blockIdx.x * 256 + tid;
    int val = (idx < N_NODES) ? counts[idx] : 0;
    buf[tid] = val;
    __syncthreads();
    for (int off = 1; off < 256; off <<= 1) {
        int t = (tid >= off) ? buf[tid - off] : 0;
        __syncthreads();
        buf[tid] += t;
        __syncthreads();
    }
    if (idx < N_NODES) row_start[idx] = buf[tid] - val;
    if (tid == 255) chunk_sum[blockIdx.x] = buf[255];
}

__global__ __launch_bounds__(128) void scan_p2(const int* __restrict__ chunk_sum,
                                               int* __restrict__ chunk_off)
{
    __shared__ int buf[128];
    const int tid = threadIdx.x;
    int val = (tid < NCHUNK) ? chunk_sum[tid] : 0;
    buf[tid] = val;
    __syncthreads();
    for (int off = 1; off < 128; off <<= 1) {
        int t = (tid >= off) ? buf[tid - off] : 0;
        __syncthreads();
        buf[tid] += t;
        __syncthreads();
    }
    if (tid < NCHUNK) chunk_off[tid] = buf[tid] - val;
}

__global__ __launch_bounds__(256) void scan_p3(int* __restrict__ row_start,
                                               const int* __restrict__ chunk_off,
                                               int* __restrict__ cursor)
{
    int idx = blockIdx.x * 256 + threadIdx.x;
    if (idx < N_NODES) {
        int vv = row_start[idx] + chunk_off[blockIdx.x];
        row_start[idx] = vv;
        cursor[idx] = vv;
    }
    if (idx == 0) row_start[N_NODES] = E_EDGES;
}

__global__ __launch_bounds__(256) void scatter_kernel(const int* __restrict__ i_index,
                                                      const int* __restrict__ j_index,
                                                      const float* __restrict__ dir,
                                                      int* __restrict__ cursor,
                                                      int* __restrict__ edge_ids,
                                                      int* __restrict__ edge_j,
                                                      float* __restrict__ edge_dir4)
{
    int e = blockIdx.x * 256 + threadIdx.x;
    if (e < E_EDGES) {
        int j = j_index[e];
        float dx = dir[(size_t)e * 3 + 0];
        float dy = dir[(size_t)e * 3 + 1];
        float dz = dir[(size_t)e * 3 + 2];
        int pos = atomicAdd(&cursor[i_index[e]], 1);
        edge_ids[pos] = e;
        edge_j[pos] = j;
        f32x4 d4 = {dx, dy, dz, 0.0f};
        *(f32x4*)(edge_dir4 + (size_t)pos * 4) = d4;
    }
}

// ---------------------------------------------------------------------------
// Kernel B: per-destination-node aggregation. R1 body (proven 172us shape:
// n = blockIdx.x -> wave-uniform edge stream, no software pipeline) plus:
//  * __launch_bounds__(128,4): 128-VGPR budget so the 60 Wr weights are
//    register-resident (removes ~60 loads + ~60 addr-VALU per edge-lane).
//    R2's spill came from the 2-edge unroll (~190 live), not this bound.
//  * edge_j / edge_dir4: no dependent e->j load; dir sequential in CSR order.
// Accumulation order identical to R1 -> bit-identical numerics.
// ---------------------------------------------------------------------------
__global__ __launch_bounds__(128, 4) void agg_kernel(
    const float* __restrict__ s, const float* __restrict__ v,
    const float* __restrict__ rbf,
    const float* __restrict__ Wr, const float* __restrict__ br,
    const float* __restrict__ h,
    const int* __restrict__ row_start, const int* __restrict__ edge_ids,
    const int* __restrict__ edge_j, const float* __restrict__ edge_dir4,
    float* __restrict__ s_agg, float* __restrict__ v_agg)
{
    const int f = threadIdx.x;
    const int n = blockIdx.x;

    float wr0[NRBF], wr1[NRBF], wr2[NRBF];
    #pragma unroll
    for (int k = 0; k < NRBF; ++k) {
        wr0[k] = Wr[k * F3 + f];
        wr1[k] = Wr[k * F3 + F + f];
        wr2[k] = Wr[k * F3 + 2 * F + f];
    }
    const float br0 = br[f], br1 = br[F + f], br2 = br[2 * F + f];

    float s_acc = s[n * F + f];
    float v0 = v[n * F3 + f * 3 + 0];
    float v1 = v[n * F3 + f * 3 + 1];
    float v2 = v[n * F3 + f * 3 + 2];

    const int beg = row_start[n];
    const int end = row_start[n + 1];
    const float cc = 0.6283185307179586f;   // pi/5

    for (int idx = beg; idx < end; ++idx) {
        const int e = edge_ids[idx];
        const int j = edge_j[idx];

        float x0 = br0, x1 = br1, x2 = br2;
        #pragma unroll
        for (int k = 0; k < NRBF; ++k) {
            float r = rbf[e * NRBF + k];
            x0 += r * wr0[k];
            x1 += r * wr1[k];
            x2 += r * wr2[k];
        }
        float w0 = (x0 < 5.0f) ? 0.5f * (__cosf(x0 * cc) + 1.0f) : 0.0f;
        float w1 = (x1 < 5.0f) ? 0.5f * (__cosf(x1 * cc) + 1.0f) : 0.0f;
        float w2 = (x2 < 5.0f) ? 0.5f * (__cosf(x2 * cc) + 1.0f) : 0.0f;

        float hs  = h[j * F3 + f]         * w0;
        float hvs = h[j * F3 + F + f]     * w1;
        float hvv = h[j * F3 + 2 * F + f] * w2;

        float dx = edge_dir4[idx * 4 + 0];
        float dy = edge_dir4[idx * 4 + 1];
        float dz = edge_dir4[idx * 4 + 2];

        float vj0 = v[j * F3 + f * 3 + 0];
        float vj1 = v[j * F3 + f * 3 + 1];
        float vj2 = v[j * F3 + f * 3 + 2];

        s_acc += hs;
        v0 += hvs * dx + hvv * vj0;
        v1 += hvs * dy + hvv * vj1;
        v2 += hvs * dz + hvv * vj2;
    }

    s_agg[n * F + f] = s_acc;
    v_agg[n * F3 + f * 3 + 0] = v0;
    v_agg[n * F3 + f * 3 + 1] = v1;
    v_agg[n * F3 + f * 3 + 2] = v2;
}

// ---------------------------------------------------------------------------
// Kernel C: per-node update via MFMA (unchanged).
// ---------------------------------------------------------------------------
#define UB 16
__global__ __launch_bounds__(256) void update_mfma(
    const float* __restrict__ s_agg, const float* __restrict__ v_agg,
    const unsigned short* __restrict__ WUVs,
    const float* __restrict__ bU, const float* __restrict__ bV,
    const unsigned short* __restrict__ M1s, const float* __restrict__ bm1,
    const unsigned short* __restrict__ M2s, const float* __restrict__ bm2,
    float* __restrict__ s_out, float* __restrict__ v_out)
{
    __shared__ unsigned short VAh[48][SLD],  VAl[48][SLD];
    __shared__ unsigned short MIh[16][264],  MIl[16][264];
    __shared__ unsigned short HIh[16][SLD],  HIl[16][SLD];

    const int tid = threadIdx.x;
    const int lane = tid & 63, wave = tid >> 6;
    const int m = lane & 15, quad = lane >> 4;
    const int n0 = blockIdx.x * UB;

    for (int i = tid; i < UB * F3; i += 256) {
        int nl = i / F3, r = i - nl * F3;
        int f = r / 3, d = r - f * 3;
        unsigned short hi, lo;
        bf_split(v_agg[(size_t)n0 * F3 + i], hi, lo);
        VAh[d * 16 + nl][f] = hi;
        VAl[d * 16 + nl][f] = lo;
    }
    __syncthreads();

    f32x4 accU[3][2], accV[3][2];
    #pragma unroll
    for (int d = 0; d < 3; ++d)
        #pragma unroll
        for (int c = 0; c < 2; ++c) {
            accU[d][c] = (f32x4){0.f, 0.f, 0.f, 0.f};
            accV[d][c] = (f32x4){0.f, 0.f, 0.f, 0.f};
        }

    const bf16x8* Wf  = (const bf16x8*)WUVs;
    #pragma unroll
    for (int kc = 0; kc < 4; ++kc) {
        bf16x8 bu0 = Wf[((wave * 2 + 0) * 4 + kc) * 64 + lane];
        bf16x8 bu1 = Wf[((wave * 2 + 1) * 4 + kc) * 64 + lane];
        bf16x8 bv0 = Wf[((8 + wave * 2 + 0) * 4 + kc) * 64 + lane];
        bf16x8 bv1 = Wf[((8 + wave * 2 + 1) * 4 + kc) * 64 + lane];
        #pragma unroll
        for (int d = 0; d < 3; ++d) {
            bf16x8 ah = *(const bf16x8*)&VAh[d * 16 + m][kc * 32 + quad * 8];
            bf16x8 al = *(const bf16x8*)&VAl[d * 16 + m][kc * 32 + quad * 8];
            accU[d][0] = __builtin_amdgcn_mfma_f32_16x16x32_bf16(ah, bu0, accU[d][0], 0, 0, 0);
            accU[d][0] = __builtin_amdgcn_mfma_f32_16x16x32_bf16(al, bu0, accU[d][0], 0, 0, 0);
            accU[d][1] = __builtin_amdgcn_mfma_f32_16x16x32_bf16(ah, bu1, accU[d][1], 0, 0, 0);
            accU[d][1] = __builtin_amdgcn_mfma_f32_16x16x32_bf16(al, bu1, accU[d][1], 0, 0, 0);
            accV[d][0] = __builtin_amdgcn_mfma_f32_16x16x32_bf16(ah, bv0, accV[d][0], 0, 0, 0);
            accV[d][0] = __builtin_amdgcn_mfma_f32_16x16x32_bf16(al, bv0, accV[d][0], 0, 0, 0);
            accV[d][1] = __builtin_amdgcn_mfma_f32_16x16x32_bf16(ah, bv1, accV[d][1], 0, 0, 0);
            accV[d][1] = __builtin_amdgcn_mfma_f32_16x16x32_bf16(al, bv1, accV[d][1], 0, 0, 0);
        }
    }

    #pragma unroll
    for (int c = 0; c < 2; ++c) {
        int g = wave * 32 + c * 16 + m;
        float bu = bU[g], bv = bV[g];
        #pragma unroll
        for (int d = 0; d < 3; ++d)
            #pragma unroll
            for (int r = 0; r < 4; ++r) {
                accU[d][c][r] += bu;
                accV[d][c][r] += bv;
            }
        #pragma unroll
        for (int r = 0; r < 4; ++r) {
            int nl = quad * 4 + r;
            float nv = sqrtf(accV[0][c][r] * accV[0][c][r] +
                             accV[1][c][r] * accV[1][c][r] +
                             accV[2][c][r] * accV[2][c][r]);
            unsigned short hi, lo;
            bf_split(nv, hi, lo);
            MIh[nl][g] = hi; MIl[nl][g] = lo;
            bf_split(s_agg[(size_t)(n0 + nl) * F + g], hi, lo);
            MIh[nl][128 + g] = hi; MIl[nl][128 + g] = lo;
        }
    }
    __syncthreads();

    f32x4 acc2[2];
    acc2[0] = (f32x4){0.f, 0.f, 0.f, 0.f};
    acc2[1] = (f32x4){0.f, 0.f, 0.f, 0.f};
    const bf16x8* M1f = (const bf16x8*)M1s;
    #pragma unroll
    for (int kc = 0; kc < 8; ++kc) {
        bf16x8 ah = *(const bf16x8*)&MIh[m][kc * 32 + quad * 8];
        bf16x8 al = *(const bf16x8*)&MIl[m][kc * 32 + quad * 8];
        bf16x8 b0 = M1f[((wave * 2 + 0) * 8 + kc) * 64 + lane];
        bf16x8 b1 = M1f[((wave * 2 + 1) * 8 + kc) * 64 + lane];
        acc2[0] = __builtin_amdgcn_mfma_f32_16x16x32_bf16(ah, b0, acc2[0], 0, 0, 0);
        acc2[0] = __builtin_amdgcn_mfma_f32_16x16x32_bf16(al, b0, acc2[0], 0, 0, 0);
        acc2[1] = __builtin_amdgcn_mfma_f32_16x16x32_bf16(ah, b1, acc2[1], 0, 0, 0);
        acc2[1] = __builtin_amdgcn_mfma_f32_16x16x32_bf16(al, b1, acc2[1], 0, 0, 0);
    }
    #pragma unroll
    for (int c = 0; c < 2; ++c) {
        int g = wave * 32 + c * 16 + m;
        float bh = bm1[g];
        #pragma unroll
        for (int r = 0; r < 4; ++r) {
            unsigned short hi, lo;
            bf_split(silu_f(acc2[c][r] + bh), hi, lo);
            HIh[quad * 4 + r][g] = hi;
            HIl[quad * 4 + r][g] = lo;
        }
    }
    __syncthreads();

    f32x4 acc3[3][2];
    #pragma unroll
    for (int o = 0; o < 3; ++o)
        #pragma unroll
        for (int c = 0; c < 2; ++c)
            acc3[o][c] = (f32x4){0.f, 0.f, 0.f, 0.f};
    const bf16x8* M2f = (const bf16x8*)M2s;
    #pragma unroll
    for (int kc = 0; kc < 4; ++kc) {
        bf16x8 ah = *(const bf16x8*)&HIh[m][kc * 32 + quad * 8];
        bf16x8 al = *(const bf16x8*)&HIl[m][kc * 32 + quad * 8];
        #pragma unroll
        for (int o = 0; o < 3; ++o)
            #pragma unroll
            for (int c = 0; c < 2; ++c) {
                bf16x8 bb = M2f[(((o * 8) + wave * 2 + c) * 4 + kc) * 64 + lane];
                acc3[o][c] = __builtin_amdgcn_mfma_f32_16x16x32_bf16(ah, bb, acc3[o][c], 0, 0, 0);
                acc3[o][c] = __builtin_amdgcn_mfma_f32_16x16x32_bf16(al, bb, acc3[o][c], 0, 0, 0);
            }
    }

    #pragma unroll
    for (int c = 0; c < 2; ++c) {
        int g = wave * 32 + c * 16 + m;
        float bvv = bm2[g], bsv = bm2[128 + g], bss = bm2[256 + g];
        #pragma unroll
        for (int r = 0; r < 4; ++r) {
            int nl = quad * 4 + r;
            int n = n0 + nl;
            float a_vv = acc3[0][c][r] + bvv;
            float a_sv = acc3[1][c][r] + bsv;
            float a_ss = acc3[2][c][r] + bss;
            float dotuv = accU[0][c][r] * accV[0][c][r] +
                          accU[1][c][r] * accV[1][c][r] +
                          accU[2][c][r] * accV[2][c][r];
            s_out[(size_t)n * F + g] =
                s_agg[(size_t)n * F + g] + dotuv * a_sv + a_ss;
            #pragma unroll
            for (int d = 0; d < 3; ++d)
                v_out[(size_t)n * F3 + g * 3 + d] =
                    v_agg[(size_t)n * F3 + g * 3 + d] + a_vv * accU[d][c][r];
        }
    }
}

// ---------------------------------------------------------------------------
extern "C" void kernel_launch(void* const* d_in, const int* in_sizes, int n_in,
                              void* d_out, int out_size, void* d_ws, size_t ws_size,
                              hipStream_t stream) {
    const float* s    = (const float*)d_in[0];
    const float* v    = (const float*)d_in[1];
    const float* rbf  = (const float*)d_in[2];
    const float* dir  = (const float*)d_in[3];
    const float* W1   = (const float*)d_in[4];
    const float* b1   = (const float*)d_in[5];
    const float* W2   = (const float*)d_in[6];
    const float* b2   = (const float*)d_in[7];
    const float* Wr   = (const float*)d_in[8];
    const float* br   = (const float*)d_in[9];
    const float* WU   = (const float*)d_in[10];
    const float* bU   = (const float*)d_in[11];
    const float* WV   = (const float*)d_in[12];
    const float* bV   = (const float*)d_in[13];
    const float* M1   = (const float*)d_in[14];
    const float* bm1  = (const float*)d_in[15];
    const float* M2   = (const float*)d_in[16];
    const float* bm2  = (const float*)d_in[17];
    const int* i_index = (const int*)d_in[18];
    const int* j_index = (const int*)d_in[19];

    float* out_s = (float*)d_out;                     // N*F
    float* out_v = out_s + (size_t)N_NODES * F;       // N*F*3

    // workspace layout
    float* h       = (float*)d_ws;                         // N*384 floats
    float* s_agg   = h + (size_t)N_NODES * F3;             // N*128
    float* v_agg   = s_agg + (size_t)N_NODES * F;          // N*384
    float* edge_dir4 = v_agg + (size_t)N_NODES * F3;       // E*4 (16B aligned)
    int*   counts  = (int*)(edge_dir4 + (size_t)E_EDGES * 4); // N
    int*   row_start = counts + N_NODES;                   // N+1
    int*   cursor  = row_start + N_NODES + 1;              // N
    int*   edge_ids = cursor + N_NODES;                    // E
    int*   edge_j  = edge_ids + E_EDGES;                   // E
    int*   chunk_sum = edge_j + E_EDGES;                   // 128
    int*   chunk_off = chunk_sum + 128;                    // 128
    unsigned short* W1s = (unsigned short*)(chunk_off + 128);  // 8*4*64*8
    unsigned short* W2s = W1s + 8 * 4 * 64 * 8;                // 24*4*64*8
    unsigned short* WUVs = W2s + 24 * 4 * 64 * 8;              // 16*4*64*8
    unsigned short* M1s  = WUVs + 16 * 4 * 64 * 8;             // 8*8*64*8
    unsigned short* M2s  = M1s + 8 * 8 * 64 * 8;               // 24*4*64*8

    hipMemsetAsync(counts, 0, sizeof(int) * N_NODES, stream);

    w_swizzle_all<<<88, 256, 0, stream>>>(W1, W2, WU, WV, M1, M2,
                                          W1s, W2s, WUVs, M1s, M2s);
    node_mlp_mfma<<<(N_NODES + 63) / 64, 256, 0, stream>>>(s, b1, b2, W1s, W2s, h);

    hist_kernel<<<(E_EDGES + 255) / 256, 256, 0, stream>>>(i_index, counts);
    scan_p1<<<NCHUNK, 256, 0, stream>>>(counts, row_start, chunk_sum);
    scan_p2<<<1, 128, 0, stream>>>(chunk_sum, chunk_off);
    scan_p3<<<NCHUNK, 256, 0, stream>>>(row_start, chunk_off, cursor);
    scatter_kernel<<<(E_EDGES + 255) / 256, 256, 0, stream>>>(i_index, j_index, dir,
                                                              cursor, edge_ids, edge_j,
                                                              edge_dir4);

    agg_kernel<<<N_NODES, 128, 0, stream>>>(s, v, rbf, Wr, br, h,
                                            row_start, edge_ids, edge_j, edge_dir4,
                                            s_agg, v_agg);

    update_mfma<<<N_NODES / UB, 256, 0, stream>>>(s_agg, v_agg, WUVs, bU, bV,
                                                  M1s, bm1, M2s, bm2, out_s, out_v);
}